// Round 18
// baseline (203.256 us; speedup 1.0000x reference)
//
#include <hip/hip_runtime.h>
#include <hip/hip_bf16.h>

typedef __attribute__((ext_vector_type(8))) short bf16x8;
typedef __attribute__((ext_vector_type(4))) float f32x4;
typedef __attribute__((ext_vector_type(4))) short short4v;

__device__ __forceinline__ unsigned short f2bf(float f) {
  union { float f; unsigned u; } x; x.f = f;
  return (unsigned short)((x.u + 0x7FFFu + ((x.u >> 16) & 1u)) >> 16);
}

__device__ __forceinline__ short f2bf_hw(float f) {
  __hip_bfloat16 h = __float2bfloat16(f);
  return *(short*)&h;
}

__device__ __forceinline__ void lds_cp16(const void* g, void* l) {
  __builtin_amdgcn_global_load_lds(
      (const __attribute__((address_space(1))) void*)g,
      (__attribute__((address_space(3))) void*)l,
      16, 0, 0);
}

#define GBAR() do { __builtin_amdgcn_s_barrier(); __builtin_amdgcn_sched_barrier(0); } while (0)

// ---------------- cast fp32 -> bf16, vectorized ----------------
__global__ __launch_bounds__(256) void cast_x(const float* __restrict__ in,
                                              short* __restrict__ out, int n4) {
  int i = blockIdx.x * 256 + threadIdx.x;
  if (i >= n4) return;
  float4 v = reinterpret_cast<const float4*>(in)[i];
  short4v o;
  o.x = (short)f2bf(v.x); o.y = (short)f2bf(v.y);
  o.z = (short)f2bf(v.z); o.w = (short)f2bf(v.w);
  reinterpret_cast<short4v*>(out)[i] = o;
}

// ---------------- fused weight transpose+cast: Wq/Wk/Wv -> Wqkv, Wo -> Wot ---
// QKV rows are PERMUTED within each 128-row head block so that the BN=192
// gemm's per-lane fragments form in-lane RoPE pairs 16 cols apart:
//   dh = gi*16 + lo4 + 64*hi  ->  off = gi*32 + hi*16 + lo4  (bijective)
__global__ __launch_bounds__(256) void transp_w(const float* __restrict__ Wq,
                                                const float* __restrict__ Wk,
                                                const float* __restrict__ Wv,
                                                const float* __restrict__ Wo,
                                                short* __restrict__ Wqkv,
                                                short* __restrict__ Wot) {
  __shared__ float t[32][33];
  const int K = 2048;
  int bnG = blockIdx.x * 32;
  int bk = blockIdx.y * 32;
  const float* src; int N, bn; short* out; int orow; bool perm;
  if (bnG < 2048)      { src = Wq; N = 2048; bn = bnG;        out = Wqkv; orow = bnG;        perm = true; }
  else if (bnG < 2560) { src = Wk; N = 512;  bn = bnG - 2048; out = Wqkv; orow = bnG;        perm = true; }
  else if (bnG < 3072) { src = Wv; N = 512;  bn = bnG - 2560; out = Wqkv; orow = bnG;        perm = true; }
  else                 { src = Wo; N = 2048; bn = bnG - 3072; out = Wot;  orow = bnG - 3072; perm = false; }
  int tx = threadIdx.x, ty = threadIdx.y;
  for (int i = ty; i < 32; i += 8)
    t[i][tx] = src[(size_t)(bk + i) * N + bn + tx];
  __syncthreads();
  for (int i = ty; i < 32; i += 8) {
    int c = orow + i;
    if (perm) {
      const int d = c & 127, hi = d >> 6, d6 = d & 63;
      c = (c & ~127) | (((d6 >> 4) << 5) | (hi << 4) | (d6 & 15));
    }
    out[(size_t)c * K + bk + tx] = (short)f2bf(t[tx][i]);
  }
}

// ---------------- bf16 transpose: per head [2048 pos][128 dh] -> [128 dh][2048 pos]
__global__ __launch_bounds__(256) void transp_v(const short* __restrict__ V,
                                                short* __restrict__ VTo) {
  __shared__ short t[32][34];
  const int hd = blockIdx.z;
  const int p0 = blockIdx.x * 32, d0 = blockIdx.y * 32;
  const short* src = V + (size_t)hd * 2048 * 128;
  short* dst = VTo + (size_t)hd * 2048 * 128;
  int tx = threadIdx.x, ty = threadIdx.y;
  for (int i = ty; i < 32; i += 8)
    t[i][tx] = src[(size_t)(p0 + i) * 128 + d0 + tx];
  __syncthreads();
  for (int i = ty; i < 32; i += 8)
    dst[(size_t)(d0 + i) * 2048 + p0 + tx] = t[tx][i];
}

// ---------------- QKV GEMM: BM=256 x BN=192, grid 16x16 = 256 blocks --------
// Full-CU fill (r17 lesson: 192 blocks left 64 CUs idle; fill-corrected rate
// matches gemm_op's ~1050 TF). LDS 112KB -> exactly 1 block/CU. Ledger is the
// r10-verified 8-loads/tile schedule: A quarters staged p0/p1, B quarters
// (48 rows, 384 active threads) staged p2 (q0,q2) / p3 (q1,q3), matching the
// nh-phase reads; vmcnt(2) at p0 and p3 only. RoPE pairs are in-lane via the
// transp_w permutation; epilogue un-permutes.
__global__ __launch_bounds__(512, 1) void gemm_qkv(
    const short* __restrict__ A, const short* __restrict__ Bt,
    short* __restrict__ Qo, short* __restrict__ Ko, short* __restrict__ Vo,
    const float* __restrict__ cosT, const float* __restrict__ sinT) {
  __shared__ __align__(16) short As[2][256 * 64];
  __shared__ __align__(16) short Bs[2][192 * 64];
  const int tid = threadIdx.x;
  const int l = tid & 63, l15 = l & 15, l4 = l >> 4;
  const int wid = tid >> 6, wr = wid >> 1, wc = wid & 1;
  const int sid = (blockIdx.x & 7) * 32 + (blockIdx.x >> 3);  // 256 % 8 == 0
  const int bm = sid & 15, bn = sid >> 4;                     // 16 x 16

  const int srow = tid >> 3;
  const int sch = tid & 7;

  auto stA = [&](int dbuf, int k0, int i) {
    const int rl = srow + i * 64;
    const int c = sch ^ (rl & 7);
    lds_cp16(A + (size_t)(bm * 256 + rl) * 2048 + k0 + c * 8,
             (char*)As[dbuf] + tid * 16 + i * 8192);
  };
  auto stB = [&](int dbuf, int k0, int q) {   // quarter q: rows q*48..q*48+47
    if (tid < 384) {
      const int rl = q * 48 + (tid >> 3);
      const int c = sch ^ (rl & 7);
      lds_cp16(Bt + (size_t)(bn * 192 + rl) * 2048 + k0 + c * 8,
               (char*)Bs[dbuf] + q * 6144 + tid * 16);
    }
  };
  auto rdA = [&](int dbuf, int m, int kb) {
    const int row = wr * 64 + m * 16 + l15;
    return *(const bf16x8*)((const char*)As[dbuf] + (row << 7) +
                            ((kb * 64 + l4 * 16) ^ ((row & 7) << 4)));
  };
  auto rdB = [&](int dbuf, int nh, int f, int kb) {
    const int row = wc * 96 + nh * 48 + f * 16 + l15;
    return *(const bf16x8*)((const char*)Bs[dbuf] + (row << 7) +
                            ((kb * 64 + l4 * 16) ^ ((row & 7) << 4)));
  };

  f32x4 acc[4][6];
#pragma unroll
  for (int m = 0; m < 4; m++)
#pragma unroll
    for (int n = 0; n < 6; n++) acc[m][n] = (f32x4){0.f, 0.f, 0.f, 0.f};

  const int NT = 32;

  // prologue: stage tile 0 completely, drain, barrier
#pragma unroll
  for (int i = 0; i < 4; i++) stA(0, 0, i);
#pragma unroll
  for (int q = 0; q < 4; q++) stB(0, 0, q);
  asm volatile("s_waitcnt vmcnt(0)" ::: "memory");
  GBAR();

  for (int kt = 0; kt < NT; kt++) {
    const int buf = kt & 1, nbf = buf ^ 1;
    const bool stg = (kt + 1 < NT);
    const int k1 = (kt + 1) << 6;
    bf16x8 a[4], b[3];

    // ---------- phase 0: nh=0, kb0 ----------
#pragma unroll
    for (int m = 0; m < 4; m++) a[m] = rdA(buf, m, 0);
#pragma unroll
    for (int f = 0; f < 3; f++) b[f] = rdB(buf, 0, f, 0);
    if (stg) { stA(nbf, k1, 0); stA(nbf, k1, 1); }
    if (stg) asm volatile("s_waitcnt vmcnt(2)" ::: "memory");
    else     asm volatile("s_waitcnt vmcnt(0)" ::: "memory");
    GBAR();
    asm volatile("s_waitcnt lgkmcnt(0)" ::: "memory");
    __builtin_amdgcn_sched_barrier(0);
    __builtin_amdgcn_s_setprio(1);
#pragma unroll
    for (int m = 0; m < 4; m++)
#pragma unroll
      for (int f = 0; f < 3; f++)
        acc[m][f] = __builtin_amdgcn_mfma_f32_16x16x32_bf16(a[m], b[f], acc[m][f], 0, 0, 0);
    __builtin_amdgcn_s_setprio(0);
    GBAR();

    // ---------- phase 1: nh=1, kb0 ----------
#pragma unroll
    for (int f = 0; f < 3; f++) b[f] = rdB(buf, 1, f, 0);
    if (stg) { stA(nbf, k1, 2); stA(nbf, k1, 3); }
    GBAR();
    asm volatile("s_waitcnt lgkmcnt(0)" ::: "memory");
    __builtin_amdgcn_sched_barrier(0);
    __builtin_amdgcn_s_setprio(1);
#pragma unroll
    for (int m = 0; m < 4; m++)
#pragma unroll
      for (int f = 0; f < 3; f++)
        acc[m][3 + f] = __builtin_amdgcn_mfma_f32_16x16x32_bf16(a[m], b[f], acc[m][3 + f], 0, 0, 0);
    __builtin_amdgcn_s_setprio(0);
    GBAR();

    // ---------- phase 2: nh=0, kb1 ----------
#pragma unroll
    for (int m = 0; m < 4; m++) a[m] = rdA(buf, m, 1);
#pragma unroll
    for (int f = 0; f < 3; f++) b[f] = rdB(buf, 0, f, 1);
    if (stg) { stB(nbf, k1, 0); stB(nbf, k1, 2); }
    GBAR();
    asm volatile("s_waitcnt lgkmcnt(0)" ::: "memory");
    __builtin_amdgcn_sched_barrier(0);
    __builtin_amdgcn_s_setprio(1);
#pragma unroll
    for (int m = 0; m < 4; m++)
#pragma unroll
      for (int f = 0; f < 3; f++)
        acc[m][f] = __builtin_amdgcn_mfma_f32_16x16x32_bf16(a[m], b[f], acc[m][f], 0, 0, 0);
    __builtin_amdgcn_s_setprio(0);
    GBAR();

    // ---------- phase 3: nh=1, kb1 ----------
#pragma unroll
    for (int f = 0; f < 3; f++) b[f] = rdB(buf, 1, f, 1);
    if (stg) { stB(nbf, k1, 1); stB(nbf, k1, 3); }
    if (stg) asm volatile("s_waitcnt vmcnt(2)" ::: "memory");
    GBAR();
    asm volatile("s_waitcnt lgkmcnt(0)" ::: "memory");
    __builtin_amdgcn_sched_barrier(0);
    __builtin_amdgcn_s_setprio(1);
#pragma unroll
    for (int m = 0; m < 4; m++)
#pragma unroll
      for (int f = 0; f < 3; f++)
        acc[m][3 + f] = __builtin_amdgcn_mfma_f32_16x16x32_bf16(a[m], b[f], acc[m][3 + f], 0, 0, 0);
    __builtin_amdgcn_s_setprio(0);
    GBAR();
  }

  // Epilogue: permuted col x_lo = bn*192 + wc*96 + p*32 + l15 (p = pair 0..2);
  // head = x_lo>>7, dh = ((x_lo>>5)&3)*16 + l15 (<64), partner dh+64.
  // acc pairs: (n=2p lo, n=2p+1 hi)  [n = nh*3+f ordering: cols 0,16,32,48,64,80]
#pragma unroll
  for (int m = 0; m < 4; m++) {
#pragma unroll
    for (int r = 0; r < 4; r++) {
      const int grow = bm * 256 + wr * 64 + m * 16 + l4 * 4 + r;
      const int bb = grow >> 11, pos = grow & 2047;
#pragma unroll
      for (int p = 0; p < 3; p++) {
        const int x_lo = bn * 192 + wc * 96 + p * 32 + l15;
        const int head = x_lo >> 7;
        const int dh = ((x_lo >> 5) & 3) * 16 + l15;
        const float xlo = acc[m][2 * p][r], xhi = acc[m][2 * p + 1][r];
        if (head < 20) {
          const float cv = cosT[pos * 128 + dh];
          const float sv = sinT[pos * 128 + dh];
          short* dst;
          if (head < 16) dst = Qo + ((size_t)(bb * 16 + head) * 2048 + pos) * 128;
          else           dst = Ko + ((size_t)(bb * 4 + (head - 16)) * 2048 + pos) * 128;
          dst[dh]      = (short)f2bf(xlo * cv - xhi * sv);
          dst[dh + 64] = (short)f2bf(xhi * cv + xlo * sv);
        } else {
          short* dst = Vo + ((size_t)(bb * 4 + (head - 20)) * 2048 + pos) * 128;
          dst[dh]      = (short)f2bf(xlo);
          dst[dh + 64] = (short)f2bf(xhi);
        }
      }
    }
  }
}

// ---------------- out-proj GEMM: 4-phase 128x128 (r15-verified ledger) -------
__global__ __launch_bounds__(512, 2) void gemm_op(
    const short* __restrict__ A, const short* __restrict__ Bt,
    float* __restrict__ C) {
  __shared__ __align__(16) short As[2][128 * 64];
  __shared__ __align__(16) short Bs[2][128 * 64];
  const int tid = threadIdx.x;
  const int l = tid & 63, l15 = l & 15, l4 = l >> 4;
  const int wid = tid >> 6, wr = wid >> 1, wc = wid & 1;
  const int sid = (blockIdx.x & 7) * 64 + (blockIdx.x >> 3);  // 512 % 8 == 0
  const int bm = sid & 31, bn = sid >> 5;
  const int srow = tid >> 3;
  const int sch = tid & 7;

  auto stA = [&](int dbuf, int k0, int i) {
    const int rl = i * 64 + srow;
    const int c = sch ^ (rl & 7);
    lds_cp16(A + (size_t)(bm * 128 + rl) * 2048 + k0 + c * 8,
             (char*)As[dbuf] + i * 8192 + tid * 16);
  };
  auto stB = [&](int dbuf, int k0, int j) {
    const int rl = j * 64 + srow;
    const int c = sch ^ (rl & 7);
    lds_cp16(Bt + (size_t)(bn * 128 + rl) * 2048 + k0 + c * 8,
             (char*)Bs[dbuf] + j * 8192 + tid * 16);
  };
  auto rdA = [&](int dbuf, int m, int kb) {
    const int row = wr * 32 + m * 16 + l15;
    return *(const bf16x8*)((const char*)As[dbuf] + (row << 7) +
                            ((kb * 64 + l4 * 16) ^ ((row & 7) << 4)));
  };
  auto rdB = [&](int dbuf, int nh, int f, int kb) {
    const int row = nh * 64 + wc * 32 + f * 16 + l15;   // nh OUTER: phase==half
    return *(const bf16x8*)((const char*)Bs[dbuf] + (row << 7) +
                            ((kb * 64 + l4 * 16) ^ ((row & 7) << 4)));
  };

  f32x4 acc[2][4];
#pragma unroll
  for (int m = 0; m < 2; m++)
#pragma unroll
    for (int n = 0; n < 4; n++) acc[m][n] = (f32x4){0.f, 0.f, 0.f, 0.f};

  const int NT = 32;

  stB(0, 0, 0); stA(0, 0, 0); stA(0, 0, 1); stB(0, 0, 1);
  asm volatile("s_waitcnt vmcnt(1)" ::: "memory");
  GBAR();

  for (int kt = 0; kt < NT; kt++) {
    const int buf = kt & 1, nbf = buf ^ 1;
    const bool stg = (kt + 1 < NT);
    const int k1 = (kt + 1) << 6;
    bf16x8 a[2][2], b[2];

    // ---------- phase 0: nh=0, kb0 ----------
#pragma unroll
    for (int m = 0; m < 2; m++) a[m][0] = rdA(buf, m, 0);
#pragma unroll
    for (int f = 0; f < 2; f++) b[f] = rdB(buf, 0, f, 0);
    if (stg) stB(nbf, k1, 0);
    GBAR();
    asm volatile("s_waitcnt lgkmcnt(0)" ::: "memory");
    __builtin_amdgcn_sched_barrier(0);
    __builtin_amdgcn_s_setprio(1);
#pragma unroll
    for (int m = 0; m < 2; m++)
#pragma unroll
      for (int f = 0; f < 2; f++)
        acc[m][f] = __builtin_amdgcn_mfma_f32_16x16x32_bf16(a[m][0], b[f], acc[m][f], 0, 0, 0);
    __builtin_amdgcn_s_setprio(0);
    GBAR();

    // ---------- phase 1: nh=0, kb1 ----------
#pragma unroll
    for (int m = 0; m < 2; m++) a[m][1] = rdA(buf, m, 1);
#pragma unroll
    for (int f = 0; f < 2; f++) b[f] = rdB(buf, 0, f, 1);
    if (stg) stA(nbf, k1, 0);
    if (stg) asm volatile("s_waitcnt vmcnt(2)" ::: "memory");
    else     asm volatile("s_waitcnt vmcnt(0)" ::: "memory");
    GBAR();
    asm volatile("s_waitcnt lgkmcnt(0)" ::: "memory");
    __builtin_amdgcn_sched_barrier(0);
    __builtin_amdgcn_s_setprio(1);
#pragma unroll
    for (int m = 0; m < 2; m++)
#pragma unroll
      for (int f = 0; f < 2; f++)
        acc[m][f] = __builtin_amdgcn_mfma_f32_16x16x32_bf16(a[m][1], b[f], acc[m][f], 0, 0, 0);
    __builtin_amdgcn_s_setprio(0);
    GBAR();

    // ---------- phase 2: nh=1, kb0 ----------
#pragma unroll
    for (int f = 0; f < 2; f++) b[f] = rdB(buf, 1, f, 0);
    if (stg) stA(nbf, k1, 1);
    GBAR();
    asm volatile("s_waitcnt lgkmcnt(0)" ::: "memory");
    __builtin_amdgcn_sched_barrier(0);
    __builtin_amdgcn_s_setprio(1);
#pragma unroll
    for (int m = 0; m < 2; m++)
#pragma unroll
      for (int f = 0; f < 2; f++)
        acc[m][2 + f] = __builtin_amdgcn_mfma_f32_16x16x32_bf16(a[m][0], b[f], acc[m][2 + f], 0, 0, 0);
    __builtin_amdgcn_s_setprio(0);
    GBAR();

    // ---------- phase 3: nh=1, kb1 ----------
#pragma unroll
    for (int f = 0; f < 2; f++) b[f] = rdB(buf, 1, f, 1);
    if (stg) stB(nbf, k1, 1);
    if (stg) asm volatile("s_waitcnt vmcnt(1)" ::: "memory");
    else     asm volatile("s_waitcnt vmcnt(0)" ::: "memory");
    GBAR();
    asm volatile("s_waitcnt lgkmcnt(0)" ::: "memory");
    __builtin_amdgcn_sched_barrier(0);
    __builtin_amdgcn_s_setprio(1);
#pragma unroll
    for (int m = 0; m < 2; m++)
#pragma unroll
      for (int f = 0; f < 2; f++)
        acc[m][2 + f] = __builtin_amdgcn_mfma_f32_16x16x32_bf16(a[m][1], b[f], acc[m][2 + f], 0, 0, 0);
    __builtin_amdgcn_s_setprio(0);
    GBAR();
  }

#pragma unroll
  for (int m = 0; m < 2; m++) {
    const int grow = bm * 128 + wr * 32 + m * 16 + l4 * 4;
#pragma unroll
    for (int n = 0; n < 4; n++) {
      const int col = bn * 128 + (n >> 1) * 64 + wc * 32 + (n & 1) * 16 + l15;
#pragma unroll
      for (int r = 0; r < 4; r++)
        C[(size_t)(grow + r) * 2048 + col] = acc[m][n][r];
    }
  }
}

// ---------------- flash attention, causal, GQA (round-10 verified) ----------
__global__ __launch_bounds__(256) void attn_fwd(
    const short* __restrict__ Q, const short* __restrict__ K,
    const short* __restrict__ VT, short* __restrict__ AO) {
  __shared__ __align__(16) short Ks[2][64 * 128];
  __shared__ __align__(16) short VTs[2][128 * 64];
  __shared__ __align__(16) short Pl[4][16 * 64];
  const int tid = threadIdx.x;
  const int w = tid >> 6, l = tid & 63;
  const int l15 = l & 15, l4 = l >> 4;
  const int bid = blockIdx.x;
  const int lg = (bid & 7) * 64 + (bid >> 3);
  const int bh = lg >> 4, pp = lg & 15;
  const int b = bh >> 4, h = bh & 15, kv = h >> 2;
  const short* Qbase = Q + (size_t)(b * 16 + h) * 2048 * 128;
  const short* Kbase = K + (size_t)(b * 4 + kv) * 2048 * 128;
  const short* VTb   = VT + (size_t)(b * 4 + kv) * 2048 * 128;

  int rk[4], ck[4], dv[4], kc[4];
#pragma unroll
  for (int i = 0; i < 4; i++) {
    const int c = tid + i * 256;
    rk[i] = c >> 4; ck[i] = (c & 15) ^ (rk[i] & 7);
    dv[i] = c >> 3; kc[i] = (c & 7) ^ (dv[i] & 7);
  }

  const float SCL = 0.08838834764831845f * 1.4426950408889634f;

  bf16x8 ones;
#pragma unroll
  for (int j = 0; j < 8; j++) ones[j] = (short)0x3F80;

  for (int qq = 0; qq < 2; qq++) {
    const int qt = qq ? (31 - pp) : pp;
    const int q0w = qt * 64 + w * 16;

    bf16x8 qf[4];
#pragma unroll
    for (int kb = 0; kb < 4; kb++)
      qf[kb] = *(const bf16x8*)(Qbase + (size_t)(q0w + l15) * 128 + kb * 32 + l4 * 8);

    f32x4 oacc[8];
#pragma unroll
    for (int i = 0; i < 8; i++) oacc[i] = (f32x4){0.f, 0.f, 0.f, 0.f};
    f32x4 lacc = (f32x4){0.f, 0.f, 0.f, 0.f};

    const int ntiles = qt + 1;

    __syncthreads();
#pragma unroll
    for (int i = 0; i < 4; i++) {
      lds_cp16(Kbase + rk[i] * 128 + ck[i] * 8, (char*)Ks[0] + i * 4096 + tid * 16);
      lds_cp16(VTb + (size_t)dv[i] * 2048 + kc[i] * 8, (char*)VTs[0] + i * 4096 + tid * 16);
    }

    for (int nt = 0; nt < ntiles; nt++) {
      const int k0 = nt * 64, buf = nt & 1;
      __syncthreads();
      if (nt + 1 < ntiles) {
        const int kn = k0 + 64, bnx = buf ^ 1;
#pragma unroll
        for (int i = 0; i < 4; i++) {
          lds_cp16(Kbase + (size_t)(kn + rk[i]) * 128 + ck[i] * 8,
                   (char*)Ks[bnx] + i * 4096 + tid * 16);
          lds_cp16(VTb + (size_t)dv[i] * 2048 + kn + kc[i] * 8,
                   (char*)VTs[bnx] + i * 4096 + tid * 16);
        }
      }

      f32x4 sa[4];
#pragma unroll
      for (int kg = 0; kg < 4; kg++) sa[kg] = (f32x4){0.f, 0.f, 0.f, 0.f};
      __builtin_amdgcn_s_setprio(1);
#pragma unroll
      for (int kg = 0; kg < 4; kg++) {
        const int row = kg * 16 + l15;
        const int swz = (row & 7) << 4;
#pragma unroll
        for (int kb = 0; kb < 4; kb++) {
          const char* kp = (const char*)Ks[buf] + row * 256 + ((kb * 64 + l4 * 16) ^ swz);
          sa[kg] = __builtin_amdgcn_mfma_f32_16x16x32_bf16(qf[kb], *(const bf16x8*)kp, sa[kg], 0, 0, 0);
        }
      }
      __builtin_amdgcn_s_setprio(0);

      float p[4][4];
      const bool domask = (k0 + 63 > q0w);
#pragma unroll
      for (int kg = 0; kg < 4; kg++)
#pragma unroll
        for (int r = 0; r < 4; r++) {
          float pv = exp2f(sa[kg][r] * SCL);
          if (domask) {
            int qrow = q0w + l4 * 4 + r;
            if (k0 + kg * 16 + l15 > qrow) pv = 0.f;
          }
          p[kg][r] = pv;
        }

#pragma unroll
      for (int r = 0; r < 4; r++) {
        const int rw = l4 * 4 + r;
        const int swz = (rw & 7) << 4;
#pragma unroll
        for (int kg = 0; kg < 4; kg++)
          *(short*)((char*)Pl[w] + (rw * 128 + ((kg * 32 + l15 * 2) ^ swz))) =
              f2bf_hw(p[kg][r]);
      }
      asm volatile("s_waitcnt lgkmcnt(0)" ::: "memory");
      bf16x8 pf[2];
#pragma unroll
      for (int ks = 0; ks < 2; ks++)
        pf[ks] = *(const bf16x8*)((const char*)Pl[w] +
                 (l15 * 128 + ((ks * 64 + l4 * 16) ^ ((l15 & 7) << 4))));

      __builtin_amdgcn_s_setprio(1);
#pragma unroll
      for (int nb = 0; nb < 8; nb++) {
        const int d = nb * 16 + l15;
        const int dsw = (d & 7) << 4;
#pragma unroll
        for (int ks = 0; ks < 2; ks++) {
          const char* vp = (const char*)VTs[buf] + d * 128 + ((ks * 64 + l4 * 16) ^ dsw);
          oacc[nb] = __builtin_amdgcn_mfma_f32_16x16x32_bf16(pf[ks], *(const bf16x8*)vp, oacc[nb], 0, 0, 0);
        }
      }
      lacc = __builtin_amdgcn_mfma_f32_16x16x32_bf16(pf[0], ones, lacc, 0, 0, 0);
      lacc = __builtin_amdgcn_mfma_f32_16x16x32_bf16(pf[1], ones, lacc, 0, 0, 0);
      __builtin_amdgcn_s_setprio(0);
    }

#pragma unroll
    for (int r = 0; r < 4; r++) {
      float inv = 1.0f / lacc[r];
      size_t rowb = ((size_t)b * 2048 + q0w + l4 * 4 + r) * 2048 + h * 128;
#pragma unroll
      for (int nb = 0; nb < 8; nb++)
        AO[rowb + nb * 16 + l15] = f2bf_hw(oacc[nb][r] * inv);
    }
  }
}

extern "C" void kernel_launch(void* const* d_in, const int* in_sizes, int n_in,
                              void* d_out, int out_size, void* d_ws, size_t ws_size,
                              hipStream_t stream) {
  const float* hs   = (const float*)d_in[0];
  const float* cosT = (const float*)d_in[1];
  const float* sinT = (const float*)d_in[2];
  const float* Wq   = (const float*)d_in[3];
  const float* Wk   = (const float*)d_in[4];
  const float* Wv   = (const float*)d_in[5];
  const float* Wo   = (const float*)d_in[6];
  float* out = (float*)d_out;

  char* p = (char*)d_ws;
  short* Xb   = (short*)p; p += (size_t)4096 * 2048 * 2;   // reused as AO
  short* Wqkv = (short*)p; p += (size_t)3072 * 2048 * 2;
  short* Wot  = (short*)p; p += (size_t)2048 * 2048 * 2;
  short* Qb   = (short*)p; p += (size_t)2 * 16 * 2048 * 128 * 2;
  short* Kb   = (short*)p; p += (size_t)2 * 4 * 2048 * 128 * 2;
  short* Vb   = (short*)p; p += (size_t)2 * 4 * 2048 * 128 * 2;
  short* VTb  = (short*)p; p += (size_t)2 * 4 * 2048 * 128 * 2;
  short* AO   = Xb;

  cast_x<<<8192, 256, 0, stream>>>(hs, Xb, 2097152);
  transp_w<<<dim3(160, 64), dim3(32, 8), 0, stream>>>(Wq, Wk, Wv, Wo, Wqkv, Wot);

  // QKV: M=4096, N=3072 -> 256 blocks (256x192 tile, 1/CU, full fill)
  gemm_qkv<<<256, 512, 0, stream>>>(Xb, Wqkv, Qb, Kb, Vb, cosT, sinT);
  transp_v<<<dim3(64, 4, 8), dim3(32, 8), 0, stream>>>(Vb, VTb);
  attn_fwd<<<512, 256, 0, stream>>>(Qb, Kb, VTb, AO);
  // out-proj: M=4096, N=2048 -> 512 blocks (2/CU, 64KB LDS)
  gemm_op<<<512, 512, 0, stream>>>(AO, Wot, out);
}

// Round 19
// 202.682 us; speedup vs baseline: 1.0028x; 1.0028x over previous
//
#include <hip/hip_runtime.h>
#include <hip/hip_bf16.h>

typedef __attribute__((ext_vector_type(8))) short bf16x8;
typedef __attribute__((ext_vector_type(4))) float f32x4;
typedef __attribute__((ext_vector_type(4))) short short4v;

__device__ __forceinline__ unsigned short f2bf(float f) {
  union { float f; unsigned u; } x; x.f = f;
  return (unsigned short)((x.u + 0x7FFFu + ((x.u >> 16) & 1u)) >> 16);
}

__device__ __forceinline__ short f2bf_hw(float f) {
  __hip_bfloat16 h = __float2bfloat16(f);
  return *(short*)&h;
}

__device__ __forceinline__ void lds_cp16(const void* g, void* l) {
  __builtin_amdgcn_global_load_lds(
      (const __attribute__((address_space(1))) void*)g,
      (__attribute__((address_space(3))) void*)l,
      16, 0, 0);
}

#define GBAR() do { __builtin_amdgcn_s_barrier(); __builtin_amdgcn_sched_barrier(0); } while (0)

// ---------------- cast fp32 -> bf16, vectorized ----------------
__global__ __launch_bounds__(256) void cast_x(const float* __restrict__ in,
                                              short* __restrict__ out, int n4) {
  int i = blockIdx.x * 256 + threadIdx.x;
  if (i >= n4) return;
  float4 v = reinterpret_cast<const float4*>(in)[i];
  short4v o;
  o.x = (short)f2bf(v.x); o.y = (short)f2bf(v.y);
  o.z = (short)f2bf(v.z); o.w = (short)f2bf(v.w);
  reinterpret_cast<short4v*>(out)[i] = o;
}

// ---------------- fused weight transpose+cast: Wq/Wk/Wv -> Wqkv, Wo -> Wot ---
__global__ __launch_bounds__(256) void transp_w(const float* __restrict__ Wq,
                                                const float* __restrict__ Wk,
                                                const float* __restrict__ Wv,
                                                const float* __restrict__ Wo,
                                                short* __restrict__ Wqkv,
                                                short* __restrict__ Wot) {
  __shared__ float t[32][33];
  const int K = 2048;
  int bnG = blockIdx.x * 32;
  int bk = blockIdx.y * 32;
  const float* src; int N, bn; short* out; int orow;
  if (bnG < 2048)      { src = Wq; N = 2048; bn = bnG;        out = Wqkv; orow = bnG; }
  else if (bnG < 2560) { src = Wk; N = 512;  bn = bnG - 2048; out = Wqkv; orow = bnG; }
  else if (bnG < 3072) { src = Wv; N = 512;  bn = bnG - 2560; out = Wqkv; orow = bnG; }
  else                 { src = Wo; N = 2048; bn = bnG - 3072; out = Wot;  orow = bnG - 3072; }
  int tx = threadIdx.x, ty = threadIdx.y;
  for (int i = ty; i < 32; i += 8)
    t[i][tx] = src[(size_t)(bk + i) * N + bn + tx];
  __syncthreads();
  for (int i = ty; i < 32; i += 8)
    out[(size_t)(orow + i) * K + bk + tx] = (short)f2bf(t[tx][i]);
}

// ---------------- bf16 transpose: per head [2048 pos][128 dh] -> [128 dh][2048 pos]
__global__ __launch_bounds__(256) void transp_v(const short* __restrict__ V,
                                                short* __restrict__ VTo) {
  __shared__ short t[32][34];
  const int hd = blockIdx.z;
  const int p0 = blockIdx.x * 32, d0 = blockIdx.y * 32;
  const short* src = V + (size_t)hd * 2048 * 128;
  short* dst = VTo + (size_t)hd * 2048 * 128;
  int tx = threadIdx.x, ty = threadIdx.y;
  for (int i = ty; i < 32; i += 8)
    t[i][tx] = src[(size_t)(p0 + i) * 128 + d0 + tx];
  __syncthreads();
  for (int i = ty; i < 32; i += 8)
    dst[(size_t)(d0 + i) * 2048 + p0 + tx] = t[tx][i];
}

// ---------------- QKV GEMM: 8-wave deep-phase, BM=BN=256 (r6/r10 verified) ---
// 256^2 tile keeps per-XCD panel fetch low (FETCH ~78MB vs 144MB at 128^2 —
// r16 lesson). r18 lesson: BN=192 full-fill is neutral (6 MFMA/phase + 384-thr
// staging cancels the fill gain) — keep the simpler 256^2.
__global__ __launch_bounds__(512, 2) void gemm_qkv(
    const short* __restrict__ A, const short* __restrict__ Bt,
    short* __restrict__ Qo, short* __restrict__ Ko, short* __restrict__ Vo,
    const float* __restrict__ cosT, const float* __restrict__ sinT) {
  constexpr int NM = 4;
  __shared__ __align__(16) short As[2][256 * 64];
  __shared__ __align__(16) short Bs[2][256 * 64];
  const int tid = threadIdx.x;
  const int l = tid & 63, l15 = l & 15, l4 = l >> 4;
  const int wid = tid >> 6, wr = wid >> 1, wc = wid & 1;
  const int sid = (blockIdx.x & 7) * 24 + (blockIdx.x >> 3);  // 192 % 8 == 0
  const int bm = sid % 16, bn = sid / 16;

  const int srow = tid >> 3;
  const int sch = tid & 7;

  auto stA = [&](int dbuf, int k0, int i) {
    const int rl = srow + i * 64;
    const int c = sch ^ (rl & 7);
    lds_cp16(A + (size_t)(bm * 256 + rl) * 2048 + k0 + c * 8,
             (char*)As[dbuf] + tid * 16 + i * 8192);
  };
  auto stB = [&](int dbuf, int k0, int j) {
    const int rl = srow + j * 64;
    const int c = sch ^ (rl & 7);
    lds_cp16(Bt + (size_t)(bn * 256 + rl) * 2048 + k0 + c * 8,
             (char*)Bs[dbuf] + tid * 16 + j * 8192);
  };
  auto rdA = [&](int dbuf, int m, int kb) {
    const int row = wr * 64 + m * 16 + l15;
    return *(const bf16x8*)((const char*)As[dbuf] + (row << 7) +
                            ((kb * 64 + l4 * 16) ^ ((row & 7) << 4)));
  };
  auto rdB = [&](int dbuf, int nh, int f, int kb) {
    const int row = wc * 128 + nh * 64 + f * 16 + l15;
    return *(const bf16x8*)((const char*)Bs[dbuf] + (row << 7) +
                            ((kb * 64 + l4 * 16) ^ ((row & 7) << 4)));
  };

  f32x4 acc[NM][8];
#pragma unroll
  for (int m = 0; m < NM; m++)
#pragma unroll
    for (int n = 0; n < 8; n++) acc[m][n] = (f32x4){0.f, 0.f, 0.f, 0.f};

  const int NT = 32;

#pragma unroll
  for (int i = 0; i < NM; i++) stA(0, 0, i);
#pragma unroll
  for (int j = 0; j < 4; j++) stB(0, 0, j);
  asm volatile("s_waitcnt vmcnt(0)" ::: "memory");
  GBAR();

  for (int kt = 0; kt < NT; kt++) {
    const int buf = kt & 1, nbf = buf ^ 1;
    const bool stg = (kt + 1 < NT);
    const int k1 = (kt + 1) << 6;
    bf16x8 a[NM], b[4];

    // ---------- phase 0 ----------
#pragma unroll
    for (int m = 0; m < NM; m++) a[m] = rdA(buf, m, 0);
#pragma unroll
    for (int f = 0; f < 4; f++) b[f] = rdB(buf, 0, f, 0);
    if (stg) { stA(nbf, k1, 0); stA(nbf, k1, 1); }
    if (stg) asm volatile("s_waitcnt vmcnt(2)" ::: "memory");
    else     asm volatile("s_waitcnt vmcnt(0)" ::: "memory");
    GBAR();
    asm volatile("s_waitcnt lgkmcnt(0)" ::: "memory");
    __builtin_amdgcn_sched_barrier(0);
    __builtin_amdgcn_s_setprio(1);
#pragma unroll
    for (int m = 0; m < NM; m++)
#pragma unroll
      for (int f = 0; f < 4; f++)
        acc[m][f] = __builtin_amdgcn_mfma_f32_16x16x32_bf16(a[m], b[f], acc[m][f], 0, 0, 0);
    __builtin_amdgcn_s_setprio(0);
    GBAR();

    // ---------- phase 1 ----------
#pragma unroll
    for (int f = 0; f < 4; f++) b[f] = rdB(buf, 1, f, 0);
    if (stg) { stA(nbf, k1, 2); stA(nbf, k1, 3); }
    GBAR();
    asm volatile("s_waitcnt lgkmcnt(0)" ::: "memory");
    __builtin_amdgcn_sched_barrier(0);
    __builtin_amdgcn_s_setprio(1);
#pragma unroll
    for (int m = 0; m < NM; m++)
#pragma unroll
      for (int f = 0; f < 4; f++)
        acc[m][4 + f] = __builtin_amdgcn_mfma_f32_16x16x32_bf16(a[m], b[f], acc[m][4 + f], 0, 0, 0);
    __builtin_amdgcn_s_setprio(0);
    GBAR();

    // ---------- phase 2 ----------
#pragma unroll
    for (int m = 0; m < NM; m++) a[m] = rdA(buf, m, 1);
#pragma unroll
    for (int f = 0; f < 4; f++) b[f] = rdB(buf, 0, f, 1);
    if (stg) { stB(nbf, k1, 0); stB(nbf, k1, 2); }
    GBAR();
    asm volatile("s_waitcnt lgkmcnt(0)" ::: "memory");
    __builtin_amdgcn_sched_barrier(0);
    __builtin_amdgcn_s_setprio(1);
#pragma unroll
    for (int m = 0; m < NM; m++)
#pragma unroll
      for (int f = 0; f < 4; f++)
        acc[m][f] = __builtin_amdgcn_mfma_f32_16x16x32_bf16(a[m], b[f], acc[m][f], 0, 0, 0);
    __builtin_amdgcn_s_setprio(0);
    GBAR();

    // ---------- phase 3 ----------
#pragma unroll
    for (int f = 0; f < 4; f++) b[f] = rdB(buf, 1, f, 1);
    if (stg) { stB(nbf, k1, 1); stB(nbf, k1, 3); }
    if (stg) asm volatile("s_waitcnt vmcnt(2)" ::: "memory");
    GBAR();
    asm volatile("s_waitcnt lgkmcnt(0)" ::: "memory");
    __builtin_amdgcn_sched_barrier(0);
    __builtin_amdgcn_s_setprio(1);
#pragma unroll
    for (int m = 0; m < NM; m++)
#pragma unroll
      for (int f = 0; f < 4; f++)
        acc[m][4 + f] = __builtin_amdgcn_mfma_f32_16x16x32_bf16(a[m], b[f], acc[m][4 + f], 0, 0, 0);
    __builtin_amdgcn_s_setprio(0);
    GBAR();
  }

  // fused RoPE epilogue: head = bn*2 + wc (one 128-col head per wave column)
  {
    const int head = bn * 2 + wc;
#pragma unroll
    for (int m = 0; m < NM; m++) {
#pragma unroll
      for (int r = 0; r < 4; r++) {
        const int grow = bm * 256 + wr * 64 + m * 16 + l4 * 4 + r;
        const int bb = grow >> 11, pos = grow & 2047;
        if (head < 20) {
          float c4[4], s4[4];
#pragma unroll
          for (int ni = 0; ni < 4; ni++) {
            const int dh = ni * 16 + l15;
            c4[ni] = cosT[pos * 128 + dh];
            s4[ni] = sinT[pos * 128 + dh];
          }
          short* dst;
          if (head < 16) dst = Qo + ((size_t)(bb * 16 + head) * 2048 + pos) * 128;
          else           dst = Ko + ((size_t)(bb * 4 + (head - 16)) * 2048 + pos) * 128;
#pragma unroll
          for (int ni = 0; ni < 4; ni++) {
            const int dh = ni * 16 + l15;
            float xlo = acc[m][ni][r], xhi = acc[m][ni + 4][r];
            dst[dh]      = (short)f2bf(xlo * c4[ni] - xhi * s4[ni]);
            dst[dh + 64] = (short)f2bf(xhi * c4[ni] + xlo * s4[ni]);
          }
        } else {
          short* dst = Vo + ((size_t)(bb * 4 + (head - 20)) * 2048 + pos) * 128;
#pragma unroll
          for (int ni = 0; ni < 8; ni++)
            dst[(ni >> 2) * 64 + (ni & 3) * 16 + l15] = (short)f2bf(acc[m][ni][r]);
        }
      }
    }
  }
}

// ---------------- out-proj GEMM: 4-phase 128x128 (r15-verified ledger) -------
__global__ __launch_bounds__(512, 2) void gemm_op(
    const short* __restrict__ A, const short* __restrict__ Bt,
    float* __restrict__ C) {
  __shared__ __align__(16) short As[2][128 * 64];
  __shared__ __align__(16) short Bs[2][128 * 64];
  const int tid = threadIdx.x;
  const int l = tid & 63, l15 = l & 15, l4 = l >> 4;
  const int wid = tid >> 6, wr = wid >> 1, wc = wid & 1;
  const int sid = (blockIdx.x & 7) * 64 + (blockIdx.x >> 3);  // 512 % 8 == 0
  const int bm = sid & 31, bn = sid >> 5;
  const int srow = tid >> 3;
  const int sch = tid & 7;

  auto stA = [&](int dbuf, int k0, int i) {
    const int rl = i * 64 + srow;
    const int c = sch ^ (rl & 7);
    lds_cp16(A + (size_t)(bm * 128 + rl) * 2048 + k0 + c * 8,
             (char*)As[dbuf] + i * 8192 + tid * 16);
  };
  auto stB = [&](int dbuf, int k0, int j) {
    const int rl = j * 64 + srow;
    const int c = sch ^ (rl & 7);
    lds_cp16(Bt + (size_t)(bn * 128 + rl) * 2048 + k0 + c * 8,
             (char*)Bs[dbuf] + j * 8192 + tid * 16);
  };
  auto rdA = [&](int dbuf, int m, int kb) {
    const int row = wr * 32 + m * 16 + l15;
    return *(const bf16x8*)((const char*)As[dbuf] + (row << 7) +
                            ((kb * 64 + l4 * 16) ^ ((row & 7) << 4)));
  };
  auto rdB = [&](int dbuf, int nh, int f, int kb) {
    const int row = nh * 64 + wc * 32 + f * 16 + l15;   // nh OUTER: phase==half
    return *(const bf16x8*)((const char*)Bs[dbuf] + (row << 7) +
                            ((kb * 64 + l4 * 16) ^ ((row & 7) << 4)));
  };

  f32x4 acc[2][4];
#pragma unroll
  for (int m = 0; m < 2; m++)
#pragma unroll
    for (int n = 0; n < 4; n++) acc[m][n] = (f32x4){0.f, 0.f, 0.f, 0.f};

  const int NT = 32;

  stB(0, 0, 0); stA(0, 0, 0); stA(0, 0, 1); stB(0, 0, 1);
  asm volatile("s_waitcnt vmcnt(1)" ::: "memory");
  GBAR();

  for (int kt = 0; kt < NT; kt++) {
    const int buf = kt & 1, nbf = buf ^ 1;
    const bool stg = (kt + 1 < NT);
    const int k1 = (kt + 1) << 6;
    bf16x8 a[2][2], b[2];

    // ---------- phase 0: nh=0, kb0 ----------
#pragma unroll
    for (int m = 0; m < 2; m++) a[m][0] = rdA(buf, m, 0);
#pragma unroll
    for (int f = 0; f < 2; f++) b[f] = rdB(buf, 0, f, 0);
    if (stg) stB(nbf, k1, 0);
    GBAR();
    asm volatile("s_waitcnt lgkmcnt(0)" ::: "memory");
    __builtin_amdgcn_sched_barrier(0);
    __builtin_amdgcn_s_setprio(1);
#pragma unroll
    for (int m = 0; m < 2; m++)
#pragma unroll
      for (int f = 0; f < 2; f++)
        acc[m][f] = __builtin_amdgcn_mfma_f32_16x16x32_bf16(a[m][0], b[f], acc[m][f], 0, 0, 0);
    __builtin_amdgcn_s_setprio(0);
    GBAR();

    // ---------- phase 1: nh=0, kb1 ----------
#pragma unroll
    for (int m = 0; m < 2; m++) a[m][1] = rdA(buf, m, 1);
#pragma unroll
    for (int f = 0; f < 2; f++) b[f] = rdB(buf, 0, f, 1);
    if (stg) stA(nbf, k1, 0);
    if (stg) asm volatile("s_waitcnt vmcnt(2)" ::: "memory");
    else     asm volatile("s_waitcnt vmcnt(0)" ::: "memory");
    GBAR();
    asm volatile("s_waitcnt lgkmcnt(0)" ::: "memory");
    __builtin_amdgcn_sched_barrier(0);
    __builtin_amdgcn_s_setprio(1);
#pragma unroll
    for (int m = 0; m < 2; m++)
#pragma unroll
      for (int f = 0; f < 2; f++)
        acc[m][f] = __builtin_amdgcn_mfma_f32_16x16x32_bf16(a[m][1], b[f], acc[m][f], 0, 0, 0);
    __builtin_amdgcn_s_setprio(0);
    GBAR();

    // ---------- phase 2: nh=1, kb0 ----------
#pragma unroll
    for (int f = 0; f < 2; f++) b[f] = rdB(buf, 1, f, 0);
    if (stg) stA(nbf, k1, 1);
    GBAR();
    asm volatile("s_waitcnt lgkmcnt(0)" ::: "memory");
    __builtin_amdgcn_sched_barrier(0);
    __builtin_amdgcn_s_setprio(1);
#pragma unroll
    for (int m = 0; m < 2; m++)
#pragma unroll
      for (int f = 0; f < 2; f++)
        acc[m][2 + f] = __builtin_amdgcn_mfma_f32_16x16x32_bf16(a[m][0], b[f], acc[m][2 + f], 0, 0, 0);
    __builtin_amdgcn_s_setprio(0);
    GBAR();

    // ---------- phase 3: nh=1, kb1 ----------
#pragma unroll
    for (int f = 0; f < 2; f++) b[f] = rdB(buf, 1, f, 1);
    if (stg) stB(nbf, k1, 1);
    if (stg) asm volatile("s_waitcnt vmcnt(1)" ::: "memory");
    else     asm volatile("s_waitcnt vmcnt(0)" ::: "memory");
    GBAR();
    asm volatile("s_waitcnt lgkmcnt(0)" ::: "memory");
    __builtin_amdgcn_sched_barrier(0);
    __builtin_amdgcn_s_setprio(1);
#pragma unroll
    for (int m = 0; m < 2; m++)
#pragma unroll
      for (int f = 0; f < 2; f++)
        acc[m][2 + f] = __builtin_amdgcn_mfma_f32_16x16x32_bf16(a[m][1], b[f], acc[m][2 + f], 0, 0, 0);
    __builtin_amdgcn_s_setprio(0);
    GBAR();
  }

#pragma unroll
  for (int m = 0; m < 2; m++) {
    const int grow = bm * 128 + wr * 32 + m * 16 + l4 * 4;
#pragma unroll
    for (int n = 0; n < 4; n++) {
      const int col = bn * 128 + (n >> 1) * 64 + wc * 32 + (n & 1) * 16 + l15;
#pragma unroll
      for (int r = 0; r < 4; r++)
        C[(size_t)(grow + r) * 2048 + col] = acc[m][n][r];
    }
  }
}

// ---------------- flash attention, causal, GQA (round-10 verified) ----------
__global__ __launch_bounds__(256) void attn_fwd(
    const short* __restrict__ Q, const short* __restrict__ K,
    const short* __restrict__ VT, short* __restrict__ AO) {
  __shared__ __align__(16) short Ks[2][64 * 128];
  __shared__ __align__(16) short VTs[2][128 * 64];
  __shared__ __align__(16) short Pl[4][16 * 64];
  const int tid = threadIdx.x;
  const int w = tid >> 6, l = tid & 63;
  const int l15 = l & 15, l4 = l >> 4;
  const int bid = blockIdx.x;
  const int lg = (bid & 7) * 64 + (bid >> 3);
  const int bh = lg >> 4, pp = lg & 15;
  const int b = bh >> 4, h = bh & 15, kv = h >> 2;
  const short* Qbase = Q + (size_t)(b * 16 + h) * 2048 * 128;
  const short* Kbase = K + (size_t)(b * 4 + kv) * 2048 * 128;
  const short* VTb   = VT + (size_t)(b * 4 + kv) * 2048 * 128;

  int rk[4], ck[4], dv[4], kc[4];
#pragma unroll
  for (int i = 0; i < 4; i++) {
    const int c = tid + i * 256;
    rk[i] = c >> 4; ck[i] = (c & 15) ^ (rk[i] & 7);
    dv[i] = c >> 3; kc[i] = (c & 7) ^ (dv[i] & 7);
  }

  const float SCL = 0.08838834764831845f * 1.4426950408889634f;

  bf16x8 ones;
#pragma unroll
  for (int j = 0; j < 8; j++) ones[j] = (short)0x3F80;

  for (int qq = 0; qq < 2; qq++) {
    const int qt = qq ? (31 - pp) : pp;
    const int q0w = qt * 64 + w * 16;

    bf16x8 qf[4];
#pragma unroll
    for (int kb = 0; kb < 4; kb++)
      qf[kb] = *(const bf16x8*)(Qbase + (size_t)(q0w + l15) * 128 + kb * 32 + l4 * 8);

    f32x4 oacc[8];
#pragma unroll
    for (int i = 0; i < 8; i++) oacc[i] = (f32x4){0.f, 0.f, 0.f, 0.f};
    f32x4 lacc = (f32x4){0.f, 0.f, 0.f, 0.f};

    const int ntiles = qt + 1;

    __syncthreads();
#pragma unroll
    for (int i = 0; i < 4; i++) {
      lds_cp16(Kbase + rk[i] * 128 + ck[i] * 8, (char*)Ks[0] + i * 4096 + tid * 16);
      lds_cp16(VTb + (size_t)dv[i] * 2048 + kc[i] * 8, (char*)VTs[0] + i * 4096 + tid * 16);
    }

    for (int nt = 0; nt < ntiles; nt++) {
      const int k0 = nt * 64, buf = nt & 1;
      __syncthreads();
      if (nt + 1 < ntiles) {
        const int kn = k0 + 64, bnx = buf ^ 1;
#pragma unroll
        for (int i = 0; i < 4; i++) {
          lds_cp16(Kbase + (size_t)(kn + rk[i]) * 128 + ck[i] * 8,
                   (char*)Ks[bnx] + i * 4096 + tid * 16);
          lds_cp16(VTb + (size_t)dv[i] * 2048 + kn + kc[i] * 8,
                   (char*)VTs[bnx] + i * 4096 + tid * 16);
        }
      }

      f32x4 sa[4];
#pragma unroll
      for (int kg = 0; kg < 4; kg++) sa[kg] = (f32x4){0.f, 0.f, 0.f, 0.f};
      __builtin_amdgcn_s_setprio(1);
#pragma unroll
      for (int kg = 0; kg < 4; kg++) {
        const int row = kg * 16 + l15;
        const int swz = (row & 7) << 4;
#pragma unroll
        for (int kb = 0; kb < 4; kb++) {
          const char* kp = (const char*)Ks[buf] + row * 256 + ((kb * 64 + l4 * 16) ^ swz);
          sa[kg] = __builtin_amdgcn_mfma_f32_16x16x32_bf16(qf[kb], *(const bf16x8*)kp, sa[kg], 0, 0, 0);
        }
      }
      __builtin_amdgcn_s_setprio(0);

      float p[4][4];
      const bool domask = (k0 + 63 > q0w);
#pragma unroll
      for (int kg = 0; kg < 4; kg++)
#pragma unroll
        for (int r = 0; r < 4; r++) {
          float pv = exp2f(sa[kg][r] * SCL);
          if (domask) {
            int qrow = q0w + l4 * 4 + r;
            if (k0 + kg * 16 + l15 > qrow) pv = 0.f;
          }
          p[kg][r] = pv;
        }

#pragma unroll
      for (int r = 0; r < 4; r++) {
        const int rw = l4 * 4 + r;
        const int swz = (rw & 7) << 4;
#pragma unroll
        for (int kg = 0; kg < 4; kg++)
          *(short*)((char*)Pl[w] + (rw * 128 + ((kg * 32 + l15 * 2) ^ swz))) =
              f2bf_hw(p[kg][r]);
      }
      asm volatile("s_waitcnt lgkmcnt(0)" ::: "memory");
      bf16x8 pf[2];
#pragma unroll
      for (int ks = 0; ks < 2; ks++)
        pf[ks] = *(const bf16x8*)((const char*)Pl[w] +
                 (l15 * 128 + ((ks * 64 + l4 * 16) ^ ((l15 & 7) << 4))));

      __builtin_amdgcn_s_setprio(1);
#pragma unroll
      for (int nb = 0; nb < 8; nb++) {
        const int d = nb * 16 + l15;
        const int dsw = (d & 7) << 4;
#pragma unroll
        for (int ks = 0; ks < 2; ks++) {
          const char* vp = (const char*)VTs[buf] + d * 128 + ((ks * 64 + l4 * 16) ^ dsw);
          oacc[nb] = __builtin_amdgcn_mfma_f32_16x16x32_bf16(pf[ks], *(const bf16x8*)vp, oacc[nb], 0, 0, 0);
        }
      }
      lacc = __builtin_amdgcn_mfma_f32_16x16x32_bf16(pf[0], ones, lacc, 0, 0, 0);
      lacc = __builtin_amdgcn_mfma_f32_16x16x32_bf16(pf[1], ones, lacc, 0, 0, 0);
      __builtin_amdgcn_s_setprio(0);
    }

#pragma unroll
    for (int r = 0; r < 4; r++) {
      float inv = 1.0f / lacc[r];
      size_t rowb = ((size_t)b * 2048 + q0w + l4 * 4 + r) * 2048 + h * 128;
#pragma unroll
      for (int nb = 0; nb < 8; nb++)
        AO[rowb + nb * 16 + l15] = f2bf_hw(oacc[nb][r] * inv);
    }
  }
}

extern "C" void kernel_launch(void* const* d_in, const int* in_sizes, int n_in,
                              void* d_out, int out_size, void* d_ws, size_t ws_size,
                              hipStream_t stream) {
  const float* hs   = (const float*)d_in[0];
  const float* cosT = (const float*)d_in[1];
  const float* sinT = (const float*)d_in[2];
  const float* Wq   = (const float*)d_in[3];
  const float* Wk   = (const float*)d_in[4];
  const float* Wv   = (const float*)d_in[5];
  const float* Wo   = (const float*)d_in[6];
  float* out = (float*)d_out;

  char* p = (char*)d_ws;
  short* Xb   = (short*)p; p += (size_t)4096 * 2048 * 2;   // reused as AO
  short* Wqkv = (short*)p; p += (size_t)3072 * 2048 * 2;
  short* Wot  = (short*)p; p += (size_t)2048 * 2048 * 2;
  short* Qb   = (short*)p; p += (size_t)2 * 16 * 2048 * 128 * 2;
  short* Kb   = (short*)p; p += (size_t)2 * 4 * 2048 * 128 * 2;
  short* Vb   = (short*)p; p += (size_t)2 * 4 * 2048 * 128 * 2;
  short* VTb  = (short*)p; p += (size_t)2 * 4 * 2048 * 128 * 2;
  short* AO   = Xb;

  cast_x<<<8192, 256, 0, stream>>>(hs, Xb, 2097152);
  transp_w<<<dim3(160, 64), dim3(32, 8), 0, stream>>>(Wq, Wk, Wv, Wo, Wqkv, Wot);

  // QKV: M=4096, N=3072 -> 192 blocks (256^2 tile), fused RoPE epilogue
  gemm_qkv<<<192, 512, 0, stream>>>(Xb, Wqkv, Qb, Kb, Vb, cosT, sinT);
  transp_v<<<dim3(64, 4, 8), dim3(32, 8), 0, stream>>>(Vb, VTb);
  attn_fwd<<<512, 256, 0, stream>>>(Qb, Kb, VTb, AO);
  // out-proj: M=4096, N=2048 -> 512 blocks (2/CU, 64KB LDS)
  gemm_op<<<512, 512, 0, stream>>>(AO, Wot, out);
}

// Round 20
// 197.555 us; speedup vs baseline: 1.0289x; 1.0260x over previous
//
#include <hip/hip_runtime.h>
#include <hip/hip_bf16.h>

typedef __attribute__((ext_vector_type(8))) short bf16x8;
typedef __attribute__((ext_vector_type(4))) float f32x4;
typedef __attribute__((ext_vector_type(4))) short short4v;

__device__ __forceinline__ unsigned short f2bf(float f) {
  union { float f; unsigned u; } x; x.f = f;
  return (unsigned short)((x.u + 0x7FFFu + ((x.u >> 16) & 1u)) >> 16);
}

__device__ __forceinline__ short f2bf_hw(float f) {
  __hip_bfloat16 h = __float2bfloat16(f);
  return *(short*)&h;
}

__device__ __forceinline__ void lds_cp16(const void* g, void* l) {
  __builtin_amdgcn_global_load_lds(
      (const __attribute__((address_space(1))) void*)g,
      (__attribute__((address_space(3))) void*)l,
      16, 0, 0);
}

#define GBAR() do { __builtin_amdgcn_s_barrier(); __builtin_amdgcn_sched_barrier(0); } while (0)

// ---------------- cast fp32 -> bf16, vectorized ----------------
__global__ __launch_bounds__(256) void cast_x(const float* __restrict__ in,
                                              short* __restrict__ out, int n4) {
  int i = blockIdx.x * 256 + threadIdx.x;
  if (i >= n4) return;
  float4 v = reinterpret_cast<const float4*>(in)[i];
  short4v o;
  o.x = (short)f2bf(v.x); o.y = (short)f2bf(v.y);
  o.z = (short)f2bf(v.z); o.w = (short)f2bf(v.w);
  reinterpret_cast<short4v*>(out)[i] = o;
}

// ---------------- fused weight transpose+cast: Wq/Wk/Wv -> Wqkv, Wo -> Wot ---
__global__ __launch_bounds__(256) void transp_w(const float* __restrict__ Wq,
                                                const float* __restrict__ Wk,
                                                const float* __restrict__ Wv,
                                                const float* __restrict__ Wo,
                                                short* __restrict__ Wqkv,
                                                short* __restrict__ Wot) {
  __shared__ float t[32][33];
  const int K = 2048;
  int bnG = blockIdx.x * 32;
  int bk = blockIdx.y * 32;
  const float* src; int N, bn; short* out; int orow;
  if (bnG < 2048)      { src = Wq; N = 2048; bn = bnG;        out = Wqkv; orow = bnG; }
  else if (bnG < 2560) { src = Wk; N = 512;  bn = bnG - 2048; out = Wqkv; orow = bnG; }
  else if (bnG < 3072) { src = Wv; N = 512;  bn = bnG - 2560; out = Wqkv; orow = bnG; }
  else                 { src = Wo; N = 2048; bn = bnG - 3072; out = Wot;  orow = bnG - 3072; }
  int tx = threadIdx.x, ty = threadIdx.y;
  for (int i = ty; i < 32; i += 8)
    t[i][tx] = src[(size_t)(bk + i) * N + bn + tx];
  __syncthreads();
  for (int i = ty; i < 32; i += 8)
    out[(size_t)(orow + i) * K + bk + tx] = (short)f2bf(t[tx][i]);
}

// ---------------- QKV GEMM: 8-wave deep-phase, BM=BN=256 (r6/r10 verified) ---
// bn<10: Q/K heads with fused RoPE. bn>=10: V heads — epilogue writes V^T
// DIRECTLY via an LDS bounce (reusing As/Bs after the final barrier), so the
// separate transp_v kernel and the Vb buffer are eliminated.
__global__ __launch_bounds__(512, 2) void gemm_qkv(
    const short* __restrict__ A, const short* __restrict__ Bt,
    short* __restrict__ Qo, short* __restrict__ Ko, short* __restrict__ VT,
    const float* __restrict__ cosT, const float* __restrict__ sinT) {
  constexpr int NM = 4;
  __shared__ __align__(16) short As[2][256 * 64];
  __shared__ __align__(16) short Bs[2][256 * 64];
  const int tid = threadIdx.x;
  const int l = tid & 63, l15 = l & 15, l4 = l >> 4;
  const int wid = tid >> 6, wr = wid >> 1, wc = wid & 1;
  const int sid = (blockIdx.x & 7) * 24 + (blockIdx.x >> 3);  // 192 % 8 == 0
  const int bm = sid % 16, bn = sid / 16;

  const int srow = tid >> 3;
  const int sch = tid & 7;

  auto stA = [&](int dbuf, int k0, int i) {
    const int rl = srow + i * 64;
    const int c = sch ^ (rl & 7);
    lds_cp16(A + (size_t)(bm * 256 + rl) * 2048 + k0 + c * 8,
             (char*)As[dbuf] + tid * 16 + i * 8192);
  };
  auto stB = [&](int dbuf, int k0, int j) {
    const int rl = srow + j * 64;
    const int c = sch ^ (rl & 7);
    lds_cp16(Bt + (size_t)(bn * 256 + rl) * 2048 + k0 + c * 8,
             (char*)Bs[dbuf] + tid * 16 + j * 8192);
  };
  auto rdA = [&](int dbuf, int m, int kb) {
    const int row = wr * 64 + m * 16 + l15;
    return *(const bf16x8*)((const char*)As[dbuf] + (row << 7) +
                            ((kb * 64 + l4 * 16) ^ ((row & 7) << 4)));
  };
  auto rdB = [&](int dbuf, int nh, int f, int kb) {
    const int row = wc * 128 + nh * 64 + f * 16 + l15;
    return *(const bf16x8*)((const char*)Bs[dbuf] + (row << 7) +
                            ((kb * 64 + l4 * 16) ^ ((row & 7) << 4)));
  };

  f32x4 acc[NM][8];
#pragma unroll
  for (int m = 0; m < NM; m++)
#pragma unroll
    for (int n = 0; n < 8; n++) acc[m][n] = (f32x4){0.f, 0.f, 0.f, 0.f};

  const int NT = 32;

#pragma unroll
  for (int i = 0; i < NM; i++) stA(0, 0, i);
#pragma unroll
  for (int j = 0; j < 4; j++) stB(0, 0, j);
  asm volatile("s_waitcnt vmcnt(0)" ::: "memory");
  GBAR();

  for (int kt = 0; kt < NT; kt++) {
    const int buf = kt & 1, nbf = buf ^ 1;
    const bool stg = (kt + 1 < NT);
    const int k1 = (kt + 1) << 6;
    bf16x8 a[NM], b[4];

    // ---------- phase 0 ----------
#pragma unroll
    for (int m = 0; m < NM; m++) a[m] = rdA(buf, m, 0);
#pragma unroll
    for (int f = 0; f < 4; f++) b[f] = rdB(buf, 0, f, 0);
    if (stg) { stA(nbf, k1, 0); stA(nbf, k1, 1); }
    if (stg) asm volatile("s_waitcnt vmcnt(2)" ::: "memory");
    else     asm volatile("s_waitcnt vmcnt(0)" ::: "memory");
    GBAR();
    asm volatile("s_waitcnt lgkmcnt(0)" ::: "memory");
    __builtin_amdgcn_sched_barrier(0);
    __builtin_amdgcn_s_setprio(1);
#pragma unroll
    for (int m = 0; m < NM; m++)
#pragma unroll
      for (int f = 0; f < 4; f++)
        acc[m][f] = __builtin_amdgcn_mfma_f32_16x16x32_bf16(a[m], b[f], acc[m][f], 0, 0, 0);
    __builtin_amdgcn_s_setprio(0);
    GBAR();

    // ---------- phase 1 ----------
#pragma unroll
    for (int f = 0; f < 4; f++) b[f] = rdB(buf, 1, f, 0);
    if (stg) { stA(nbf, k1, 2); stA(nbf, k1, 3); }
    GBAR();
    asm volatile("s_waitcnt lgkmcnt(0)" ::: "memory");
    __builtin_amdgcn_sched_barrier(0);
    __builtin_amdgcn_s_setprio(1);
#pragma unroll
    for (int m = 0; m < NM; m++)
#pragma unroll
      for (int f = 0; f < 4; f++)
        acc[m][4 + f] = __builtin_amdgcn_mfma_f32_16x16x32_bf16(a[m], b[f], acc[m][4 + f], 0, 0, 0);
    __builtin_amdgcn_s_setprio(0);
    GBAR();

    // ---------- phase 2 ----------
#pragma unroll
    for (int m = 0; m < NM; m++) a[m] = rdA(buf, m, 1);
#pragma unroll
    for (int f = 0; f < 4; f++) b[f] = rdB(buf, 0, f, 1);
    if (stg) { stB(nbf, k1, 0); stB(nbf, k1, 2); }
    GBAR();
    asm volatile("s_waitcnt lgkmcnt(0)" ::: "memory");
    __builtin_amdgcn_sched_barrier(0);
    __builtin_amdgcn_s_setprio(1);
#pragma unroll
    for (int m = 0; m < NM; m++)
#pragma unroll
      for (int f = 0; f < 4; f++)
        acc[m][f] = __builtin_amdgcn_mfma_f32_16x16x32_bf16(a[m], b[f], acc[m][f], 0, 0, 0);
    __builtin_amdgcn_s_setprio(0);
    GBAR();

    // ---------- phase 3 ----------
#pragma unroll
    for (int f = 0; f < 4; f++) b[f] = rdB(buf, 1, f, 1);
    if (stg) { stB(nbf, k1, 1); stB(nbf, k1, 3); }
    if (stg) asm volatile("s_waitcnt vmcnt(2)" ::: "memory");
    GBAR();
    asm volatile("s_waitcnt lgkmcnt(0)" ::: "memory");
    __builtin_amdgcn_sched_barrier(0);
    __builtin_amdgcn_s_setprio(1);
#pragma unroll
    for (int m = 0; m < NM; m++)
#pragma unroll
      for (int f = 0; f < 4; f++)
        acc[m][4 + f] = __builtin_amdgcn_mfma_f32_16x16x32_bf16(a[m], b[f], acc[m][4 + f], 0, 0, 0);
    __builtin_amdgcn_s_setprio(0);
    GBAR();
  }

  if (bn < 10) {
    // Q/K heads: fused RoPE epilogue (head = bn*2 + wc, all < 20)
    const int head = bn * 2 + wc;
#pragma unroll
    for (int m = 0; m < NM; m++) {
#pragma unroll
      for (int r = 0; r < 4; r++) {
        const int grow = bm * 256 + wr * 64 + m * 16 + l4 * 4 + r;
        const int bb = grow >> 11, pos = grow & 2047;
        float c4[4], s4[4];
#pragma unroll
        for (int ni = 0; ni < 4; ni++) {
          const int dh = ni * 16 + l15;
          c4[ni] = cosT[pos * 128 + dh];
          s4[ni] = sinT[pos * 128 + dh];
        }
        short* dst;
        if (head < 16) dst = Qo + ((size_t)(bb * 16 + head) * 2048 + pos) * 128;
        else           dst = Ko + ((size_t)(bb * 4 + (head - 16)) * 2048 + pos) * 128;
#pragma unroll
        for (int ni = 0; ni < 4; ni++) {
          const int dh = ni * 16 + l15;
          float xlo = acc[m][ni][r], xhi = acc[m][ni + 4][r];
          dst[dh]      = (short)f2bf(xlo * c4[ni] - xhi * s4[ni]);
          dst[dh + 64] = (short)f2bf(xhi * c4[ni] + xlo * s4[ni]);
        }
      }
    }
  } else {
    // V heads (20..23): write V^T directly via LDS bounce. After the final
    // GBAR all LDS reads are done -> As/Bs reusable. wc=0 head -> As buffer,
    // wc=1 head -> Bs buffer. Layout Tv[dh][pos_local] (128 x 256 bf16, 64KB),
    // chunk-swizzled: logical 8-pos chunk q stored at slot q^(dh&7).
    short* Tv = (wc == 0) ? (short*)As : (short*)Bs;
#pragma unroll
    for (int m = 0; m < NM; m++) {
#pragma unroll
      for (int r = 0; r < 4; r++) {
        const int pl = wr * 64 + m * 16 + l4 * 4 + r;   // pos_local 0..255
        const int q = pl >> 3, o = pl & 7;
#pragma unroll
        for (int ni = 0; ni < 8; ni++) {
          const int dh = (ni >> 2) * 64 + (ni & 3) * 16 + l15;
          *(short*)((char*)Tv + dh * 512 + (((q ^ (dh & 7)) << 4) | (o * 2))) =
              (short)f2bf(acc[m][ni][r]);
        }
      }
    }
    __syncthreads();
    const int bb2 = (bm * 256) >> 11, pos0 = (bm * 256) & 2047;
#pragma unroll
    for (int h2 = 0; h2 < 2; h2++) {
      const short* Ts = h2 ? (const short*)Bs : (const short*)As;
      const int hv = (bn - 10) * 2 + h2;               // V head index 0..3
      short* dstb = VT + (size_t)(bb2 * 4 + hv) * 2048 * 128;
#pragma unroll
      for (int pass = 0; pass < 8; pass++) {
        const int dh = (tid >> 5) + 16 * pass;         // 0..127
        const int cc = tid & 31;                        // 8-pos chunk 0..31
        bf16x8 v = *(const bf16x8*)((const char*)Ts + dh * 512 + ((cc ^ (dh & 7)) << 4));
        *(bf16x8*)(dstb + (size_t)dh * 2048 + pos0 + cc * 8) = v;
      }
    }
  }
}

// ---------------- out-proj GEMM: 4-phase 128x128 (r15-verified ledger) -------
__global__ __launch_bounds__(512, 2) void gemm_op(
    const short* __restrict__ A, const short* __restrict__ Bt,
    float* __restrict__ C) {
  __shared__ __align__(16) short As[2][128 * 64];
  __shared__ __align__(16) short Bs[2][128 * 64];
  const int tid = threadIdx.x;
  const int l = tid & 63, l15 = l & 15, l4 = l >> 4;
  const int wid = tid >> 6, wr = wid >> 1, wc = wid & 1;
  const int sid = (blockIdx.x & 7) * 64 + (blockIdx.x >> 3);  // 512 % 8 == 0
  const int bm = sid & 31, bn = sid >> 5;
  const int srow = tid >> 3;
  const int sch = tid & 7;

  auto stA = [&](int dbuf, int k0, int i) {
    const int rl = i * 64 + srow;
    const int c = sch ^ (rl & 7);
    lds_cp16(A + (size_t)(bm * 128 + rl) * 2048 + k0 + c * 8,
             (char*)As[dbuf] + i * 8192 + tid * 16);
  };
  auto stB = [&](int dbuf, int k0, int j) {
    const int rl = j * 64 + srow;
    const int c = sch ^ (rl & 7);
    lds_cp16(Bt + (size_t)(bn * 128 + rl) * 2048 + k0 + c * 8,
             (char*)Bs[dbuf] + j * 8192 + tid * 16);
  };
  auto rdA = [&](int dbuf, int m, int kb) {
    const int row = wr * 32 + m * 16 + l15;
    return *(const bf16x8*)((const char*)As[dbuf] + (row << 7) +
                            ((kb * 64 + l4 * 16) ^ ((row & 7) << 4)));
  };
  auto rdB = [&](int dbuf, int nh, int f, int kb) {
    const int row = nh * 64 + wc * 32 + f * 16 + l15;   // nh OUTER: phase==half
    return *(const bf16x8*)((const char*)Bs[dbuf] + (row << 7) +
                            ((kb * 64 + l4 * 16) ^ ((row & 7) << 4)));
  };

  f32x4 acc[2][4];
#pragma unroll
  for (int m = 0; m < 2; m++)
#pragma unroll
    for (int n = 0; n < 4; n++) acc[m][n] = (f32x4){0.f, 0.f, 0.f, 0.f};

  const int NT = 32;

  stB(0, 0, 0); stA(0, 0, 0); stA(0, 0, 1); stB(0, 0, 1);
  asm volatile("s_waitcnt vmcnt(1)" ::: "memory");
  GBAR();

  for (int kt = 0; kt < NT; kt++) {
    const int buf = kt & 1, nbf = buf ^ 1;
    const bool stg = (kt + 1 < NT);
    const int k1 = (kt + 1) << 6;
    bf16x8 a[2][2], b[2];

    // ---------- phase 0: nh=0, kb0 ----------
#pragma unroll
    for (int m = 0; m < 2; m++) a[m][0] = rdA(buf, m, 0);
#pragma unroll
    for (int f = 0; f < 2; f++) b[f] = rdB(buf, 0, f, 0);
    if (stg) stB(nbf, k1, 0);
    GBAR();
    asm volatile("s_waitcnt lgkmcnt(0)" ::: "memory");
    __builtin_amdgcn_sched_barrier(0);
    __builtin_amdgcn_s_setprio(1);
#pragma unroll
    for (int m = 0; m < 2; m++)
#pragma unroll
      for (int f = 0; f < 2; f++)
        acc[m][f] = __builtin_amdgcn_mfma_f32_16x16x32_bf16(a[m][0], b[f], acc[m][f], 0, 0, 0);
    __builtin_amdgcn_s_setprio(0);
    GBAR();

    // ---------- phase 1: nh=0, kb1 ----------
#pragma unroll
    for (int m = 0; m < 2; m++) a[m][1] = rdA(buf, m, 1);
#pragma unroll
    for (int f = 0; f < 2; f++) b[f] = rdB(buf, 0, f, 1);
    if (stg) stA(nbf, k1, 0);
    if (stg) asm volatile("s_waitcnt vmcnt(2)" ::: "memory");
    else     asm volatile("s_waitcnt vmcnt(0)" ::: "memory");
    GBAR();
    asm volatile("s_waitcnt lgkmcnt(0)" ::: "memory");
    __builtin_amdgcn_sched_barrier(0);
    __builtin_amdgcn_s_setprio(1);
#pragma unroll
    for (int m = 0; m < 2; m++)
#pragma unroll
      for (int f = 0; f < 2; f++)
        acc[m][f] = __builtin_amdgcn_mfma_f32_16x16x32_bf16(a[m][1], b[f], acc[m][f], 0, 0, 0);
    __builtin_amdgcn_s_setprio(0);
    GBAR();

    // ---------- phase 2: nh=1, kb0 ----------
#pragma unroll
    for (int f = 0; f < 2; f++) b[f] = rdB(buf, 1, f, 0);
    if (stg) stA(nbf, k1, 1);
    GBAR();
    asm volatile("s_waitcnt lgkmcnt(0)" ::: "memory");
    __builtin_amdgcn_sched_barrier(0);
    __builtin_amdgcn_s_setprio(1);
#pragma unroll
    for (int m = 0; m < 2; m++)
#pragma unroll
      for (int f = 0; f < 2; f++)
        acc[m][2 + f] = __builtin_amdgcn_mfma_f32_16x16x32_bf16(a[m][0], b[f], acc[m][2 + f], 0, 0, 0);
    __builtin_amdgcn_s_setprio(0);
    GBAR();

    // ---------- phase 3: nh=1, kb1 ----------
#pragma unroll
    for (int f = 0; f < 2; f++) b[f] = rdB(buf, 1, f, 1);
    if (stg) stB(nbf, k1, 1);
    if (stg) asm volatile("s_waitcnt vmcnt(1)" ::: "memory");
    else     asm volatile("s_waitcnt vmcnt(0)" ::: "memory");
    GBAR();
    asm volatile("s_waitcnt lgkmcnt(0)" ::: "memory");
    __builtin_amdgcn_sched_barrier(0);
    __builtin_amdgcn_s_setprio(1);
#pragma unroll
    for (int m = 0; m < 2; m++)
#pragma unroll
      for (int f = 0; f < 2; f++)
        acc[m][2 + f] = __builtin_amdgcn_mfma_f32_16x16x32_bf16(a[m][1], b[f], acc[m][2 + f], 0, 0, 0);
    __builtin_amdgcn_s_setprio(0);
    GBAR();
  }

#pragma unroll
  for (int m = 0; m < 2; m++) {
    const int grow = bm * 128 + wr * 32 + m * 16 + l4 * 4;
#pragma unroll
    for (int n = 0; n < 4; n++) {
      const int col = bn * 128 + (n >> 1) * 64 + wc * 32 + (n & 1) * 16 + l15;
#pragma unroll
      for (int r = 0; r < 4; r++)
        C[(size_t)(grow + r) * 2048 + col] = acc[m][n][r];
    }
  }
}

// ---------------- flash attention, causal, GQA (round-10 verified) ----------
__global__ __launch_bounds__(256) void attn_fwd(
    const short* __restrict__ Q, const short* __restrict__ K,
    const short* __restrict__ VT, short* __restrict__ AO) {
  __shared__ __align__(16) short Ks[2][64 * 128];
  __shared__ __align__(16) short VTs[2][128 * 64];
  __shared__ __align__(16) short Pl[4][16 * 64];
  const int tid = threadIdx.x;
  const int w = tid >> 6, l = tid & 63;
  const int l15 = l & 15, l4 = l >> 4;
  const int bid = blockIdx.x;
  const int lg = (bid & 7) * 64 + (bid >> 3);
  const int bh = lg >> 4, pp = lg & 15;
  const int b = bh >> 4, h = bh & 15, kv = h >> 2;
  const short* Qbase = Q + (size_t)(b * 16 + h) * 2048 * 128;
  const short* Kbase = K + (size_t)(b * 4 + kv) * 2048 * 128;
  const short* VTb   = VT + (size_t)(b * 4 + kv) * 2048 * 128;

  int rk[4], ck[4], dv[4], kc[4];
#pragma unroll
  for (int i = 0; i < 4; i++) {
    const int c = tid + i * 256;
    rk[i] = c >> 4; ck[i] = (c & 15) ^ (rk[i] & 7);
    dv[i] = c >> 3; kc[i] = (c & 7) ^ (dv[i] & 7);
  }

  const float SCL = 0.08838834764831845f * 1.4426950408889634f;

  bf16x8 ones;
#pragma unroll
  for (int j = 0; j < 8; j++) ones[j] = (short)0x3F80;

  for (int qq = 0; qq < 2; qq++) {
    const int qt = qq ? (31 - pp) : pp;
    const int q0w = qt * 64 + w * 16;

    bf16x8 qf[4];
#pragma unroll
    for (int kb = 0; kb < 4; kb++)
      qf[kb] = *(const bf16x8*)(Qbase + (size_t)(q0w + l15) * 128 + kb * 32 + l4 * 8);

    f32x4 oacc[8];
#pragma unroll
    for (int i = 0; i < 8; i++) oacc[i] = (f32x4){0.f, 0.f, 0.f, 0.f};
    f32x4 lacc = (f32x4){0.f, 0.f, 0.f, 0.f};

    const int ntiles = qt + 1;

    __syncthreads();
#pragma unroll
    for (int i = 0; i < 4; i++) {
      lds_cp16(Kbase + rk[i] * 128 + ck[i] * 8, (char*)Ks[0] + i * 4096 + tid * 16);
      lds_cp16(VTb + (size_t)dv[i] * 2048 + kc[i] * 8, (char*)VTs[0] + i * 4096 + tid * 16);
    }

    for (int nt = 0; nt < ntiles; nt++) {
      const int k0 = nt * 64, buf = nt & 1;
      __syncthreads();
      if (nt + 1 < ntiles) {
        const int kn = k0 + 64, bnx = buf ^ 1;
#pragma unroll
        for (int i = 0; i < 4; i++) {
          lds_cp16(Kbase + (size_t)(kn + rk[i]) * 128 + ck[i] * 8,
                   (char*)Ks[bnx] + i * 4096 + tid * 16);
          lds_cp16(VTb + (size_t)dv[i] * 2048 + kn + kc[i] * 8,
                   (char*)VTs[bnx] + i * 4096 + tid * 16);
        }
      }

      f32x4 sa[4];
#pragma unroll
      for (int kg = 0; kg < 4; kg++) sa[kg] = (f32x4){0.f, 0.f, 0.f, 0.f};
      __builtin_amdgcn_s_setprio(1);
#pragma unroll
      for (int kg = 0; kg < 4; kg++) {
        const int row = kg * 16 + l15;
        const int swz = (row & 7) << 4;
#pragma unroll
        for (int kb = 0; kb < 4; kb++) {
          const char* kp = (const char*)Ks[buf] + row * 256 + ((kb * 64 + l4 * 16) ^ swz);
          sa[kg] = __builtin_amdgcn_mfma_f32_16x16x32_bf16(qf[kb], *(const bf16x8*)kp, sa[kg], 0, 0, 0);
        }
      }
      __builtin_amdgcn_s_setprio(0);

      float p[4][4];
      const bool domask = (k0 + 63 > q0w);
#pragma unroll
      for (int kg = 0; kg < 4; kg++)
#pragma unroll
        for (int r = 0; r < 4; r++) {
          float pv = exp2f(sa[kg][r] * SCL);
          if (domask) {
            int qrow = q0w + l4 * 4 + r;
            if (k0 + kg * 16 + l15 > qrow) pv = 0.f;
          }
          p[kg][r] = pv;
        }

#pragma unroll
      for (int r = 0; r < 4; r++) {
        const int rw = l4 * 4 + r;
        const int swz = (rw & 7) << 4;
#pragma unroll
        for (int kg = 0; kg < 4; kg++)
          *(short*)((char*)Pl[w] + (rw * 128 + ((kg * 32 + l15 * 2) ^ swz))) =
              f2bf_hw(p[kg][r]);
      }
      asm volatile("s_waitcnt lgkmcnt(0)" ::: "memory");
      bf16x8 pf[2];
#pragma unroll
      for (int ks = 0; ks < 2; ks++)
        pf[ks] = *(const bf16x8*)((const char*)Pl[w] +
                 (l15 * 128 + ((ks * 64 + l4 * 16) ^ ((l15 & 7) << 4))));

      __builtin_amdgcn_s_setprio(1);
#pragma unroll
      for (int nb = 0; nb < 8; nb++) {
        const int d = nb * 16 + l15;
        const int dsw = (d & 7) << 4;
#pragma unroll
        for (int ks = 0; ks < 2; ks++) {
          const char* vp = (const char*)VTs[buf] + d * 128 + ((ks * 64 + l4 * 16) ^ dsw);
          oacc[nb] = __builtin_amdgcn_mfma_f32_16x16x32_bf16(pf[ks], *(const bf16x8*)vp, oacc[nb], 0, 0, 0);
        }
      }
      lacc = __builtin_amdgcn_mfma_f32_16x16x32_bf16(pf[0], ones, lacc, 0, 0, 0);
      lacc = __builtin_amdgcn_mfma_f32_16x16x32_bf16(pf[1], ones, lacc, 0, 0, 0);
      __builtin_amdgcn_s_setprio(0);
    }

#pragma unroll
    for (int r = 0; r < 4; r++) {
      float inv = 1.0f / lacc[r];
      size_t rowb = ((size_t)b * 2048 + q0w + l4 * 4 + r) * 2048 + h * 128;
#pragma unroll
      for (int nb = 0; nb < 8; nb++)
        AO[rowb + nb * 16 + l15] = f2bf_hw(oacc[nb][r] * inv);
    }
  }
}

extern "C" void kernel_launch(void* const* d_in, const int* in_sizes, int n_in,
                              void* d_out, int out_size, void* d_ws, size_t ws_size,
                              hipStream_t stream) {
  const float* hs   = (const float*)d_in[0];
  const float* cosT = (const float*)d_in[1];
  const float* sinT = (const float*)d_in[2];
  const float* Wq   = (const float*)d_in[3];
  const float* Wk   = (const float*)d_in[4];
  const float* Wv   = (const float*)d_in[5];
  const float* Wo   = (const float*)d_in[6];
  float* out = (float*)d_out;

  char* p = (char*)d_ws;
  short* Xb   = (short*)p; p += (size_t)4096 * 2048 * 2;   // reused as AO
  short* Wqkv = (short*)p; p += (size_t)3072 * 2048 * 2;
  short* Wot  = (short*)p; p += (size_t)2048 * 2048 * 2;
  short* Qb   = (short*)p; p += (size_t)2 * 16 * 2048 * 128 * 2;
  short* Kb   = (short*)p; p += (size_t)2 * 4 * 2048 * 128 * 2;
  short* VTb  = (short*)p; p += (size_t)2 * 4 * 2048 * 128 * 2;
  short* AO   = Xb;

  cast_x<<<8192, 256, 0, stream>>>(hs, Xb, 2097152);
  transp_w<<<dim3(160, 64), dim3(32, 8), 0, stream>>>(Wq, Wk, Wv, Wo, Wqkv, Wot);

  // QKV: M=4096, N=3072 -> 192 blocks (256^2 tile), fused RoPE + V^T epilogue
  gemm_qkv<<<192, 512, 0, stream>>>(Xb, Wqkv, Qb, Kb, VTb, cosT, sinT);
  attn_fwd<<<512, 256, 0, stream>>>(Qb, Kb, VTb, AO);
  // out-proj: M=4096, N=2048 -> 512 blocks (2/CU, 64KB LDS)
  gemm_op<<<512, 512, 0, stream>>>(AO, Wot, out);
}

// Round 21
// 195.373 us; speedup vs baseline: 1.0403x; 1.0112x over previous
//
#include <hip/hip_runtime.h>
#include <hip/hip_bf16.h>

typedef __attribute__((ext_vector_type(8))) short bf16x8;
typedef __attribute__((ext_vector_type(4))) float f32x4;
typedef __attribute__((ext_vector_type(4))) short short4v;

__device__ __forceinline__ unsigned short f2bf(float f) {
  union { float f; unsigned u; } x; x.f = f;
  return (unsigned short)((x.u + 0x7FFFu + ((x.u >> 16) & 1u)) >> 16);
}

__device__ __forceinline__ short f2bf_hw(float f) {
  __hip_bfloat16 h = __float2bfloat16(f);
  return *(short*)&h;
}

__device__ __forceinline__ void lds_cp16(const void* g, void* l) {
  __builtin_amdgcn_global_load_lds(
      (const __attribute__((address_space(1))) void*)g,
      (__attribute__((address_space(3))) void*)l,
      16, 0, 0);
}

#define GBAR() do { __builtin_amdgcn_s_barrier(); __builtin_amdgcn_sched_barrier(0); } while (0)

// ---------------- fused prep: cast X -> bf16  +  weight transpose+cast -------
// blocks [0, 8192): cast hs (2M float4). blocks [8192, 18432): transp_w tiles
// (160 x 64 grid flattened). One launch replaces two (saves launch/drain gap).
__global__ __launch_bounds__(256) void prep(const float* __restrict__ hs,
                                            short* __restrict__ Xb,
                                            const float* __restrict__ Wq,
                                            const float* __restrict__ Wk,
                                            const float* __restrict__ Wv,
                                            const float* __restrict__ Wo,
                                            short* __restrict__ Wqkv,
                                            short* __restrict__ Wot) {
  const int tx = threadIdx.x, ty = threadIdx.y;
  const int tid = ty * 32 + tx;
  const int bid = blockIdx.x;
  if (bid < 8192) {
    // cast X: fp32 -> bf16, float4-vectorized
    const int i = bid * 256 + tid;
    float4 v = reinterpret_cast<const float4*>(hs)[i];
    short4v o;
    o.x = (short)f2bf(v.x); o.y = (short)f2bf(v.y);
    o.z = (short)f2bf(v.z); o.w = (short)f2bf(v.w);
    reinterpret_cast<short4v*>(Xb)[i] = o;
    return;
  }
  // weight transpose+cast: in KxN fp32 -> out NxK bf16 (32x32 tiles)
  __shared__ float t[32][33];
  const int idx = bid - 8192;
  const int bnG = (idx % 160) * 32;
  const int bk  = (idx / 160) * 32;
  const int K = 2048;
  const float* src; int N, bn; short* out; int orow;
  if (bnG < 2048)      { src = Wq; N = 2048; bn = bnG;        out = Wqkv; orow = bnG; }
  else if (bnG < 2560) { src = Wk; N = 512;  bn = bnG - 2048; out = Wqkv; orow = bnG; }
  else if (bnG < 3072) { src = Wv; N = 512;  bn = bnG - 2560; out = Wqkv; orow = bnG; }
  else                 { src = Wo; N = 2048; bn = bnG - 3072; out = Wot;  orow = bnG - 3072; }
  for (int i = ty; i < 32; i += 8)
    t[i][tx] = src[(size_t)(bk + i) * N + bn + tx];
  __syncthreads();
  for (int i = ty; i < 32; i += 8)
    out[(size_t)(orow + i) * K + bk + tx] = (short)f2bf(t[tx][i]);
}

// ---------------- QKV GEMM: 8-wave deep-phase, BM=BN=256 (r6/r10 verified) ---
// bn<10: Q/K heads with fused RoPE. bn>=10: V heads — epilogue writes V^T
// directly via an LDS bounce (reusing As/Bs after the final barrier).
__global__ __launch_bounds__(512, 2) void gemm_qkv(
    const short* __restrict__ A, const short* __restrict__ Bt,
    short* __restrict__ Qo, short* __restrict__ Ko, short* __restrict__ VT,
    const float* __restrict__ cosT, const float* __restrict__ sinT) {
  constexpr int NM = 4;
  __shared__ __align__(16) short As[2][256 * 64];
  __shared__ __align__(16) short Bs[2][256 * 64];
  const int tid = threadIdx.x;
  const int l = tid & 63, l15 = l & 15, l4 = l >> 4;
  const int wid = tid >> 6, wr = wid >> 1, wc = wid & 1;
  const int sid = (blockIdx.x & 7) * 24 + (blockIdx.x >> 3);  // 192 % 8 == 0
  const int bm = sid % 16, bn = sid / 16;

  const int srow = tid >> 3;
  const int sch = tid & 7;

  auto stA = [&](int dbuf, int k0, int i) {
    const int rl = srow + i * 64;
    const int c = sch ^ (rl & 7);
    lds_cp16(A + (size_t)(bm * 256 + rl) * 2048 + k0 + c * 8,
             (char*)As[dbuf] + tid * 16 + i * 8192);
  };
  auto stB = [&](int dbuf, int k0, int j) {
    const int rl = srow + j * 64;
    const int c = sch ^ (rl & 7);
    lds_cp16(Bt + (size_t)(bn * 256 + rl) * 2048 + k0 + c * 8,
             (char*)Bs[dbuf] + tid * 16 + j * 8192);
  };
  auto rdA = [&](int dbuf, int m, int kb) {
    const int row = wr * 64 + m * 16 + l15;
    return *(const bf16x8*)((const char*)As[dbuf] + (row << 7) +
                            ((kb * 64 + l4 * 16) ^ ((row & 7) << 4)));
  };
  auto rdB = [&](int dbuf, int nh, int f, int kb) {
    const int row = wc * 128 + nh * 64 + f * 16 + l15;
    return *(const bf16x8*)((const char*)Bs[dbuf] + (row << 7) +
                            ((kb * 64 + l4 * 16) ^ ((row & 7) << 4)));
  };

  f32x4 acc[NM][8];
#pragma unroll
  for (int m = 0; m < NM; m++)
#pragma unroll
    for (int n = 0; n < 8; n++) acc[m][n] = (f32x4){0.f, 0.f, 0.f, 0.f};

  const int NT = 32;

#pragma unroll
  for (int i = 0; i < NM; i++) stA(0, 0, i);
#pragma unroll
  for (int j = 0; j < 4; j++) stB(0, 0, j);
  asm volatile("s_waitcnt vmcnt(0)" ::: "memory");
  GBAR();

  for (int kt = 0; kt < NT; kt++) {
    const int buf = kt & 1, nbf = buf ^ 1;
    const bool stg = (kt + 1 < NT);
    const int k1 = (kt + 1) << 6;
    bf16x8 a[NM], b[4];

    // ---------- phase 0 ----------
#pragma unroll
    for (int m = 0; m < NM; m++) a[m] = rdA(buf, m, 0);
#pragma unroll
    for (int f = 0; f < 4; f++) b[f] = rdB(buf, 0, f, 0);
    if (stg) { stA(nbf, k1, 0); stA(nbf, k1, 1); }
    if (stg) asm volatile("s_waitcnt vmcnt(2)" ::: "memory");
    else     asm volatile("s_waitcnt vmcnt(0)" ::: "memory");
    GBAR();
    asm volatile("s_waitcnt lgkmcnt(0)" ::: "memory");
    __builtin_amdgcn_sched_barrier(0);
    __builtin_amdgcn_s_setprio(1);
#pragma unroll
    for (int m = 0; m < NM; m++)
#pragma unroll
      for (int f = 0; f < 4; f++)
        acc[m][f] = __builtin_amdgcn_mfma_f32_16x16x32_bf16(a[m], b[f], acc[m][f], 0, 0, 0);
    __builtin_amdgcn_s_setprio(0);
    GBAR();

    // ---------- phase 1 ----------
#pragma unroll
    for (int f = 0; f < 4; f++) b[f] = rdB(buf, 1, f, 0);
    if (stg) { stA(nbf, k1, 2); stA(nbf, k1, 3); }
    GBAR();
    asm volatile("s_waitcnt lgkmcnt(0)" ::: "memory");
    __builtin_amdgcn_sched_barrier(0);
    __builtin_amdgcn_s_setprio(1);
#pragma unroll
    for (int m = 0; m < NM; m++)
#pragma unroll
      for (int f = 0; f < 4; f++)
        acc[m][4 + f] = __builtin_amdgcn_mfma_f32_16x16x32_bf16(a[m], b[f], acc[m][4 + f], 0, 0, 0);
    __builtin_amdgcn_s_setprio(0);
    GBAR();

    // ---------- phase 2 ----------
#pragma unroll
    for (int m = 0; m < NM; m++) a[m] = rdA(buf, m, 1);
#pragma unroll
    for (int f = 0; f < 4; f++) b[f] = rdB(buf, 0, f, 1);
    if (stg) { stB(nbf, k1, 0); stB(nbf, k1, 2); }
    GBAR();
    asm volatile("s_waitcnt lgkmcnt(0)" ::: "memory");
    __builtin_amdgcn_sched_barrier(0);
    __builtin_amdgcn_s_setprio(1);
#pragma unroll
    for (int m = 0; m < NM; m++)
#pragma unroll
      for (int f = 0; f < 4; f++)
        acc[m][f] = __builtin_amdgcn_mfma_f32_16x16x32_bf16(a[m], b[f], acc[m][f], 0, 0, 0);
    __builtin_amdgcn_s_setprio(0);
    GBAR();

    // ---------- phase 3 ----------
#pragma unroll
    for (int f = 0; f < 4; f++) b[f] = rdB(buf, 1, f, 1);
    if (stg) { stB(nbf, k1, 1); stB(nbf, k1, 3); }
    if (stg) asm volatile("s_waitcnt vmcnt(2)" ::: "memory");
    GBAR();
    asm volatile("s_waitcnt lgkmcnt(0)" ::: "memory");
    __builtin_amdgcn_sched_barrier(0);
    __builtin_amdgcn_s_setprio(1);
#pragma unroll
    for (int m = 0; m < NM; m++)
#pragma unroll
      for (int f = 0; f < 4; f++)
        acc[m][4 + f] = __builtin_amdgcn_mfma_f32_16x16x32_bf16(a[m], b[f], acc[m][4 + f], 0, 0, 0);
    __builtin_amdgcn_s_setprio(0);
    GBAR();
  }

  if (bn < 10) {
    // Q/K heads: fused RoPE epilogue (head = bn*2 + wc, all < 20)
    const int head = bn * 2 + wc;
#pragma unroll
    for (int m = 0; m < NM; m++) {
#pragma unroll
      for (int r = 0; r < 4; r++) {
        const int grow = bm * 256 + wr * 64 + m * 16 + l4 * 4 + r;
        const int bb = grow >> 11, pos = grow & 2047;
        float c4[4], s4[4];
#pragma unroll
        for (int ni = 0; ni < 4; ni++) {
          const int dh = ni * 16 + l15;
          c4[ni] = cosT[pos * 128 + dh];
          s4[ni] = sinT[pos * 128 + dh];
        }
        short* dst;
        if (head < 16) dst = Qo + ((size_t)(bb * 16 + head) * 2048 + pos) * 128;
        else           dst = Ko + ((size_t)(bb * 4 + (head - 16)) * 2048 + pos) * 128;
#pragma unroll
        for (int ni = 0; ni < 4; ni++) {
          const int dh = ni * 16 + l15;
          float xlo = acc[m][ni][r], xhi = acc[m][ni + 4][r];
          dst[dh]      = (short)f2bf(xlo * c4[ni] - xhi * s4[ni]);
          dst[dh + 64] = (short)f2bf(xhi * c4[ni] + xlo * s4[ni]);
        }
      }
    }
  } else {
    // V heads (20..23): write V^T directly via LDS bounce (r20 verified).
    short* Tv = (wc == 0) ? (short*)As : (short*)Bs;
#pragma unroll
    for (int m = 0; m < NM; m++) {
#pragma unroll
      for (int r = 0; r < 4; r++) {
        const int pl = wr * 64 + m * 16 + l4 * 4 + r;   // pos_local 0..255
        const int q = pl >> 3, o = pl & 7;
#pragma unroll
        for (int ni = 0; ni < 8; ni++) {
          const int dh = (ni >> 2) * 64 + (ni & 3) * 16 + l15;
          *(short*)((char*)Tv + dh * 512 + (((q ^ (dh & 7)) << 4) | (o * 2))) =
              (short)f2bf(acc[m][ni][r]);
        }
      }
    }
    __syncthreads();
    const int bb2 = (bm * 256) >> 11, pos0 = (bm * 256) & 2047;
#pragma unroll
    for (int h2 = 0; h2 < 2; h2++) {
      const short* Ts = h2 ? (const short*)Bs : (const short*)As;
      const int hv = (bn - 10) * 2 + h2;               // V head index 0..3
      short* dstb = VT + (size_t)(bb2 * 4 + hv) * 2048 * 128;
#pragma unroll
      for (int pass = 0; pass < 8; pass++) {
        const int dh = (tid >> 5) + 16 * pass;         // 0..127
        const int cc = tid & 31;                        // 8-pos chunk 0..31
        bf16x8 v = *(const bf16x8*)((const char*)Ts + dh * 512 + ((cc ^ (dh & 7)) << 4));
        *(bf16x8*)(dstb + (size_t)dh * 2048 + pos0 + cc * 8) = v;
      }
    }
  }
}

// ---------------- out-proj GEMM: 4-phase 128x128 (r15-verified ledger) -------
__global__ __launch_bounds__(512, 2) void gemm_op(
    const short* __restrict__ A, const short* __restrict__ Bt,
    float* __restrict__ C) {
  __shared__ __align__(16) short As[2][128 * 64];
  __shared__ __align__(16) short Bs[2][128 * 64];
  const int tid = threadIdx.x;
  const int l = tid & 63, l15 = l & 15, l4 = l >> 4;
  const int wid = tid >> 6, wr = wid >> 1, wc = wid & 1;
  const int sid = (blockIdx.x & 7) * 64 + (blockIdx.x >> 3);  // 512 % 8 == 0
  const int bm = sid & 31, bn = sid >> 5;
  const int srow = tid >> 3;
  const int sch = tid & 7;

  auto stA = [&](int dbuf, int k0, int i) {
    const int rl = i * 64 + srow;
    const int c = sch ^ (rl & 7);
    lds_cp16(A + (size_t)(bm * 128 + rl) * 2048 + k0 + c * 8,
             (char*)As[dbuf] + i * 8192 + tid * 16);
  };
  auto stB = [&](int dbuf, int k0, int j) {
    const int rl = j * 64 + srow;
    const int c = sch ^ (rl & 7);
    lds_cp16(Bt + (size_t)(bn * 128 + rl) * 2048 + k0 + c * 8,
             (char*)Bs[dbuf] + j * 8192 + tid * 16);
  };
  auto rdA = [&](int dbuf, int m, int kb) {
    const int row = wr * 32 + m * 16 + l15;
    return *(const bf16x8*)((const char*)As[dbuf] + (row << 7) +
                            ((kb * 64 + l4 * 16) ^ ((row & 7) << 4)));
  };
  auto rdB = [&](int dbuf, int nh, int f, int kb) {
    const int row = nh * 64 + wc * 32 + f * 16 + l15;   // nh OUTER: phase==half
    return *(const bf16x8*)((const char*)Bs[dbuf] + (row << 7) +
                            ((kb * 64 + l4 * 16) ^ ((row & 7) << 4)));
  };

  f32x4 acc[2][4];
#pragma unroll
  for (int m = 0; m < 2; m++)
#pragma unroll
    for (int n = 0; n < 4; n++) acc[m][n] = (f32x4){0.f, 0.f, 0.f, 0.f};

  const int NT = 32;

  stB(0, 0, 0); stA(0, 0, 0); stA(0, 0, 1); stB(0, 0, 1);
  asm volatile("s_waitcnt vmcnt(1)" ::: "memory");
  GBAR();

  for (int kt = 0; kt < NT; kt++) {
    const int buf = kt & 1, nbf = buf ^ 1;
    const bool stg = (kt + 1 < NT);
    const int k1 = (kt + 1) << 6;
    bf16x8 a[2][2], b[2];

    // ---------- phase 0: nh=0, kb0 ----------
#pragma unroll
    for (int m = 0; m < 2; m++) a[m][0] = rdA(buf, m, 0);
#pragma unroll
    for (int f = 0; f < 2; f++) b[f] = rdB(buf, 0, f, 0);
    if (stg) stB(nbf, k1, 0);
    GBAR();
    asm volatile("s_waitcnt lgkmcnt(0)" ::: "memory");
    __builtin_amdgcn_sched_barrier(0);
    __builtin_amdgcn_s_setprio(1);
#pragma unroll
    for (int m = 0; m < 2; m++)
#pragma unroll
      for (int f = 0; f < 2; f++)
        acc[m][f] = __builtin_amdgcn_mfma_f32_16x16x32_bf16(a[m][0], b[f], acc[m][f], 0, 0, 0);
    __builtin_amdgcn_s_setprio(0);
    GBAR();

    // ---------- phase 1: nh=0, kb1 ----------
#pragma unroll
    for (int m = 0; m < 2; m++) a[m][1] = rdA(buf, m, 1);
#pragma unroll
    for (int f = 0; f < 2; f++) b[f] = rdB(buf, 0, f, 1);
    if (stg) stA(nbf, k1, 0);
    if (stg) asm volatile("s_waitcnt vmcnt(2)" ::: "memory");
    else     asm volatile("s_waitcnt vmcnt(0)" ::: "memory");
    GBAR();
    asm volatile("s_waitcnt lgkmcnt(0)" ::: "memory");
    __builtin_amdgcn_sched_barrier(0);
    __builtin_amdgcn_s_setprio(1);
#pragma unroll
    for (int m = 0; m < 2; m++)
#pragma unroll
      for (int f = 0; f < 2; f++)
        acc[m][f] = __builtin_amdgcn_mfma_f32_16x16x32_bf16(a[m][1], b[f], acc[m][f], 0, 0, 0);
    __builtin_amdgcn_s_setprio(0);
    GBAR();

    // ---------- phase 2: nh=1, kb0 ----------
#pragma unroll
    for (int f = 0; f < 2; f++) b[f] = rdB(buf, 1, f, 0);
    if (stg) stA(nbf, k1, 1);
    GBAR();
    asm volatile("s_waitcnt lgkmcnt(0)" ::: "memory");
    __builtin_amdgcn_sched_barrier(0);
    __builtin_amdgcn_s_setprio(1);
#pragma unroll
    for (int m = 0; m < 2; m++)
#pragma unroll
      for (int f = 0; f < 2; f++)
        acc[m][2 + f] = __builtin_amdgcn_mfma_f32_16x16x32_bf16(a[m][0], b[f], acc[m][2 + f], 0, 0, 0);
    __builtin_amdgcn_s_setprio(0);
    GBAR();

    // ---------- phase 3: nh=1, kb1 ----------
#pragma unroll
    for (int f = 0; f < 2; f++) b[f] = rdB(buf, 1, f, 1);
    if (stg) stB(nbf, k1, 1);
    if (stg) asm volatile("s_waitcnt vmcnt(1)" ::: "memory");
    else     asm volatile("s_waitcnt vmcnt(0)" ::: "memory");
    GBAR();
    asm volatile("s_waitcnt lgkmcnt(0)" ::: "memory");
    __builtin_amdgcn_sched_barrier(0);
    __builtin_amdgcn_s_setprio(1);
#pragma unroll
    for (int m = 0; m < 2; m++)
#pragma unroll
      for (int f = 0; f < 2; f++)
        acc[m][2 + f] = __builtin_amdgcn_mfma_f32_16x16x32_bf16(a[m][1], b[f], acc[m][2 + f], 0, 0, 0);
    __builtin_amdgcn_s_setprio(0);
    GBAR();
  }

#pragma unroll
  for (int m = 0; m < 2; m++) {
    const int grow = bm * 128 + wr * 32 + m * 16 + l4 * 4;
#pragma unroll
    for (int n = 0; n < 4; n++) {
      const int col = bn * 128 + (n >> 1) * 64 + wc * 32 + (n & 1) * 16 + l15;
#pragma unroll
      for (int r = 0; r < 4; r++)
        C[(size_t)(grow + r) * 2048 + col] = acc[m][n][r];
    }
  }
}

// ---------------- flash attention, causal, GQA (round-10 verified) ----------
__global__ __launch_bounds__(256) void attn_fwd(
    const short* __restrict__ Q, const short* __restrict__ K,
    const short* __restrict__ VT, short* __restrict__ AO) {
  __shared__ __align__(16) short Ks[2][64 * 128];
  __shared__ __align__(16) short VTs[2][128 * 64];
  __shared__ __align__(16) short Pl[4][16 * 64];
  const int tid = threadIdx.x;
  const int w = tid >> 6, l = tid & 63;
  const int l15 = l & 15, l4 = l >> 4;
  const int bid = blockIdx.x;
  const int lg = (bid & 7) * 64 + (bid >> 3);
  const int bh = lg >> 4, pp = lg & 15;
  const int b = bh >> 4, h = bh & 15, kv = h >> 2;
  const short* Qbase = Q + (size_t)(b * 16 + h) * 2048 * 128;
  const short* Kbase = K + (size_t)(b * 4 + kv) * 2048 * 128;
  const short* VTb   = VT + (size_t)(b * 4 + kv) * 2048 * 128;

  int rk[4], ck[4], dv[4], kc[4];
#pragma unroll
  for (int i = 0; i < 4; i++) {
    const int c = tid + i * 256;
    rk[i] = c >> 4; ck[i] = (c & 15) ^ (rk[i] & 7);
    dv[i] = c >> 3; kc[i] = (c & 7) ^ (dv[i] & 7);
  }

  const float SCL = 0.08838834764831845f * 1.4426950408889634f;

  bf16x8 ones;
#pragma unroll
  for (int j = 0; j < 8; j++) ones[j] = (short)0x3F80;

  for (int qq = 0; qq < 2; qq++) {
    const int qt = qq ? (31 - pp) : pp;
    const int q0w = qt * 64 + w * 16;

    bf16x8 qf[4];
#pragma unroll
    for (int kb = 0; kb < 4; kb++)
      qf[kb] = *(const bf16x8*)(Qbase + (size_t)(q0w + l15) * 128 + kb * 32 + l4 * 8);

    f32x4 oacc[8];
#pragma unroll
    for (int i = 0; i < 8; i++) oacc[i] = (f32x4){0.f, 0.f, 0.f, 0.f};
    f32x4 lacc = (f32x4){0.f, 0.f, 0.f, 0.f};

    const int ntiles = qt + 1;

    __syncthreads();
#pragma unroll
    for (int i = 0; i < 4; i++) {
      lds_cp16(Kbase + rk[i] * 128 + ck[i] * 8, (char*)Ks[0] + i * 4096 + tid * 16);
      lds_cp16(VTb + (size_t)dv[i] * 2048 + kc[i] * 8, (char*)VTs[0] + i * 4096 + tid * 16);
    }

    for (int nt = 0; nt < ntiles; nt++) {
      const int k0 = nt * 64, buf = nt & 1;
      __syncthreads();
      if (nt + 1 < ntiles) {
        const int kn = k0 + 64, bnx = buf ^ 1;
#pragma unroll
        for (int i = 0; i < 4; i++) {
          lds_cp16(Kbase + (size_t)(kn + rk[i]) * 128 + ck[i] * 8,
                   (char*)Ks[bnx] + i * 4096 + tid * 16);
          lds_cp16(VTb + (size_t)dv[i] * 2048 + kn + kc[i] * 8,
                   (char*)VTs[bnx] + i * 4096 + tid * 16);
        }
      }

      f32x4 sa[4];
#pragma unroll
      for (int kg = 0; kg < 4; kg++) sa[kg] = (f32x4){0.f, 0.f, 0.f, 0.f};
      __builtin_amdgcn_s_setprio(1);
#pragma unroll
      for (int kg = 0; kg < 4; kg++) {
        const int row = kg * 16 + l15;
        const int swz = (row & 7) << 4;
#pragma unroll
        for (int kb = 0; kb < 4; kb++) {
          const char* kp = (const char*)Ks[buf] + row * 256 + ((kb * 64 + l4 * 16) ^ swz);
          sa[kg] = __builtin_amdgcn_mfma_f32_16x16x32_bf16(qf[kb], *(const bf16x8*)kp, sa[kg], 0, 0, 0);
        }
      }
      __builtin_amdgcn_s_setprio(0);

      float p[4][4];
      const bool domask = (k0 + 63 > q0w);
#pragma unroll
      for (int kg = 0; kg < 4; kg++)
#pragma unroll
        for (int r = 0; r < 4; r++) {
          float pv = exp2f(sa[kg][r] * SCL);
          if (domask) {
            int qrow = q0w + l4 * 4 + r;
            if (k0 + kg * 16 + l15 > qrow) pv = 0.f;
          }
          p[kg][r] = pv;
        }

#pragma unroll
      for (int r = 0; r < 4; r++) {
        const int rw = l4 * 4 + r;
        const int swz = (rw & 7) << 4;
#pragma unroll
        for (int kg = 0; kg < 4; kg++)
          *(short*)((char*)Pl[w] + (rw * 128 + ((kg * 32 + l15 * 2) ^ swz))) =
              f2bf_hw(p[kg][r]);
      }
      asm volatile("s_waitcnt lgkmcnt(0)" ::: "memory");
      bf16x8 pf[2];
#pragma unroll
      for (int ks = 0; ks < 2; ks++)
        pf[ks] = *(const bf16x8*)((const char*)Pl[w] +
                 (l15 * 128 + ((ks * 64 + l4 * 16) ^ ((l15 & 7) << 4))));

      __builtin_amdgcn_s_setprio(1);
#pragma unroll
      for (int nb = 0; nb < 8; nb++) {
        const int d = nb * 16 + l15;
        const int dsw = (d & 7) << 4;
#pragma unroll
        for (int ks = 0; ks < 2; ks++) {
          const char* vp = (const char*)VTs[buf] + d * 128 + ((ks * 64 + l4 * 16) ^ dsw);
          oacc[nb] = __builtin_amdgcn_mfma_f32_16x16x32_bf16(pf[ks], *(const bf16x8*)vp, oacc[nb], 0, 0, 0);
        }
      }
      lacc = __builtin_amdgcn_mfma_f32_16x16x32_bf16(pf[0], ones, lacc, 0, 0, 0);
      lacc = __builtin_amdgcn_mfma_f32_16x16x32_bf16(pf[1], ones, lacc, 0, 0, 0);
      __builtin_amdgcn_s_setprio(0);
    }

#pragma unroll
    for (int r = 0; r < 4; r++) {
      float inv = 1.0f / lacc[r];
      size_t rowb = ((size_t)b * 2048 + q0w + l4 * 4 + r) * 2048 + h * 128;
#pragma unroll
      for (int nb = 0; nb < 8; nb++)
        AO[rowb + nb * 16 + l15] = f2bf_hw(oacc[nb][r] * inv);
    }
  }
}

extern "C" void kernel_launch(void* const* d_in, const int* in_sizes, int n_in,
                              void* d_out, int out_size, void* d_ws, size_t ws_size,
                              hipStream_t stream) {
  const float* hs   = (const float*)d_in[0];
  const float* cosT = (const float*)d_in[1];
  const float* sinT = (const float*)d_in[2];
  const float* Wq   = (const float*)d_in[3];
  const float* Wk   = (const float*)d_in[4];
  const float* Wv   = (const float*)d_in[5];
  const float* Wo   = (const float*)d_in[6];
  float* out = (float*)d_out;

  char* p = (char*)d_ws;
  short* Xb   = (short*)p; p += (size_t)4096 * 2048 * 2;   // reused as AO
  short* Wqkv = (short*)p; p += (size_t)3072 * 2048 * 2;
  short* Wot  = (short*)p; p += (size_t)2048 * 2048 * 2;
  short* Qb   = (short*)p; p += (size_t)2 * 16 * 2048 * 128 * 2;
  short* Kb   = (short*)p; p += (size_t)2 * 4 * 2048 * 128 * 2;
  short* VTb  = (short*)p; p += (size_t)2 * 4 * 2048 * 128 * 2;
  short* AO   = Xb;

  // fused prep: cast X (blocks 0..8191) + weight transposes (8192..18431)
  prep<<<18432, dim3(32, 8), 0, stream>>>(hs, Xb, Wq, Wk, Wv, Wo, Wqkv, Wot);

  // QKV: M=4096, N=3072 -> 192 blocks (256^2 tile), fused RoPE + V^T epilogue
  gemm_qkv<<<192, 512, 0, stream>>>(Xb, Wqkv, Qb, Kb, VTb, cosT, sinT);
  attn_fwd<<<512, 256, 0, stream>>>(Qb, Kb, VTb, AO);
  // out-proj: M=4096, N=2048 -> 512 blocks (2/CU, 64KB LDS)
  gemm_op<<<512, 512, 0, stream>>>(AO, Wot, out);
}